// Round 15
// baseline (1391.992 us; speedup 1.0000x reference)
//
#include <hip/hip_runtime.h>
#include <stdint.h>

#define B_ 4
#define H_ 16
#define S_ 2048
#define D_ 64
#define QBLK 16
#define NTH 1024
#define NWAVES 16
#define KSLAB 128                     /* per-wave k coverage */
#define NWIN 4                        /* 32-k windows per slab */
#define ETS 136                       /* etile row stride in shorts (128 + 8 pad) */

typedef __attribute__((ext_vector_type(8))) short short8;
typedef __attribute__((ext_vector_type(4))) float float4v;
typedef __attribute__((ext_vector_type(4))) unsigned int uint4v;
typedef __attribute__((ext_vector_type(2))) unsigned int uint2v;

static __device__ __forceinline__ short f2bf(float f) {
  uint32_t u = __builtin_bit_cast(uint32_t, f);
  u = (u + 0x7FFFu + ((u >> 16) & 1u)) >> 16;   // RNE
  return (short)u;
}
static __device__ __forceinline__ float bf2f(uint32_t s) {
  return __builtin_bit_cast(float, s << 16);
}
static __device__ __forceinline__ uint32_t cvtpk(float lo, float hi) {
  uint32_t r;
  asm("v_cvt_pk_bf16_f32 %0, %1, %2" : "=v"(r) : "v"(lo), "v"(hi));
  return r;
}
static __device__ __forceinline__ uint32_t nz4(uint32_t d) {
  uint32_t x = (d & 0x7F7F7F7Fu) + 0x7F7F7F7Fu;
  x = (x | d) & 0x80808080u;
  return x >> 7;
}
static __device__ __forceinline__ uint32_t nib(uint32_t d) {
  return ((nz4(d) * 0x01020408u) >> 24) & 0xFu;
}

// dynamic LDS layout (bytes)
#define ETILE_BYTES (NWAVES * 16 * ETS * 2)        // 69632
#define MBITS_OFF   ETILE_BYTES
#define CBUF_OFF    (MBITS_OFF + QBLK * 65 * 4)    // +4160
#define LSUM_OFF    (CBUF_OFF + QBLK * 65 * 4)     // +4160
#define LINV_OFF    (LSUM_OFF + 64)
#define SMEM_BYTES  (LINV_OFF + 64)                // 78080 -> 2 blocks/CU, 32 waves

#define KBF_OFF    ((size_t)64)
#define KBF_BYTES  ((size_t)B_ * H_ * S_ * D_ * 2)
#define VT_OFF     (KBF_OFF + KBF_BYTES)
#define VT_BYTES   ((size_t)B_ * H_ * S_ * D_ * 2)

__global__ void detect_mask_dtype(const uint8_t* __restrict__ m, uint32_t* flag) {
  uint32_t a = 0, b = 0;
  for (int i = threadIdx.x; i < 65536; i += 256) {
    uint8_t x = m[i];
    if (i & 3) a |= x; else b |= x;
  }
  uint32_t bits = (a ? 1u : 0u) | (b ? 2u : 0u);
  if (bits) atomicOr(flag, bits);
}

__global__ __launch_bounds__(256) void prep_k(const float* __restrict__ K,
                                              short* __restrict__ Kbf) {
  size_t base = ((size_t)blockIdx.x * 256 + threadIdx.x) * 8;
  float4v a = __builtin_nontemporal_load((const float4v*)(K + base));
  float4v b = __builtin_nontemporal_load((const float4v*)(K + base + 4));
  short8 o;
  o[0]=f2bf(a.x); o[1]=f2bf(a.y); o[2]=f2bf(a.z); o[3]=f2bf(a.w);
  o[4]=f2bf(b.x); o[5]=f2bf(b.y); o[6]=f2bf(b.z); o[7]=f2bf(b.w);
  *(short8*)(Kbf + base) = o;
}

__global__ __launch_bounds__(256) void prep_vt(const float* __restrict__ V,
                                               short* __restrict__ VT) {
  __shared__ short tile[64][72];
  int bh = blockIdx.x >> 5, k0 = (blockIdx.x & 31) * 64;
  const float* src = V + ((size_t)bh * S_ + k0) * D_;
  int t = threadIdx.x;
  int r = t >> 2, c0 = (t & 3) * 16;
#pragma unroll
  for (int j = 0; j < 4; ++j) {
    float4v f = __builtin_nontemporal_load((const float4v*)(src + (size_t)r * D_ + c0 + j * 4));
    tile[r][c0 + j*4 + 0] = f2bf(f.x);
    tile[r][c0 + j*4 + 1] = f2bf(f.y);
    tile[r][c0 + j*4 + 2] = f2bf(f.z);
    tile[r][c0 + j*4 + 3] = f2bf(f.w);
  }
  __syncthreads();
  int d = t >> 2, ks0 = (t & 3) * 16;
  short* dst = VT + (size_t)bh * D_ * S_ + (size_t)d * S_ + k0 + ks0;
#pragma unroll
  for (int half = 0; half < 2; ++half) {
    short8 o;
#pragma unroll
    for (int i = 0; i < 8; ++i) o[i] = tile[ks0 + half * 8 + i][d];
    *(short8*)(dst + half * 8) = o;
  }
}

template <int PREP>
__global__ __launch_bounds__(NTH, 8) void attn_fused(
    const float* __restrict__ Q, const float* __restrict__ K,
    const float* __restrict__ V, const float* __restrict__ scale_p,
    const uint8_t* __restrict__ M, const uint32_t* __restrict__ flag,
    const short* __restrict__ Kbf, const short* __restrict__ VT,
    float* __restrict__ outC, float* __restrict__ outA)
{
  extern __shared__ char smem[];
  short*    etileA = (short*)smem;                      // [NWAVES][16][ETS]
  uint32_t* mbits  = (uint32_t*)(smem + MBITS_OFF);     // [QBLK][65]
  float*    cbuf   = (float*)(smem + CBUF_OFF);         // [QBLK][65]
  float*    lsum   = (float*)(smem + LSUM_OFF);
  float*    linv   = (float*)(smem + LINV_OFF);

  // bh-chunked XCD swizzle: 8192 blocks, XCD x gets bx [x*1024, x*1024+1024) = 8 bh
  const int bx  = (blockIdx.x & 7) * 1024 + (blockIdx.x >> 3);
  const int bh  = bx >> 7;
  const int q0  = (bx & 127) * QBLK;

  const int tid  = threadIdx.x;
  const int w    = tid >> 6;
  const int lane = tid & 63;
  const int g    = lane >> 4;
  const int c    = lane & 15;
  const int kslab0 = w * KSLAB;

  const float scale = scale_p[0];
  const uint32_t fl = flag[0];

  const float* Qp  = Q + (size_t)bh * S_ * D_;
  const short* Kbp = Kbf + (size_t)bh * S_ * D_;
  const short* VTp = VT + (size_t)bh * D_ * S_;
  const float* Kfp = K + (size_t)bh * S_ * D_;
  const float* Vfp = V + (size_t)bh * S_ * D_;
  short* etile = etileA + w * 16 * ETS;

  // ---- mask bitmap prologue: [16][2048] bits, 1 word/thread ----
  {
    const int row = tid >> 6;
    const int wq  = tid & 63;
    if (fl == 3u) {                            // byte mask
      const uint8_t* mrow = M + ((size_t)(bh * S_ + q0 + row)) * S_ + wq * 32;
      uint4v a = __builtin_nontemporal_load((const uint4v*)mrow);
      uint4v b = __builtin_nontemporal_load((const uint4v*)(mrow + 16));
      mbits[row * 65 + wq] =
          nib(a.x) | (nib(a.y) << 4) | (nib(a.z) << 8)  | (nib(a.w) << 12)
        | (nib(b.x) << 16) | (nib(b.y) << 20) | (nib(b.z) << 24) | (nib(b.w) << 28);
    } else {                                   // 4-byte mask
      const uint32_t* mrow = (const uint32_t*)M + ((size_t)(bh * S_ + q0 + row)) * S_ + wq * 32;
      uint32_t bits = 0;
#pragma unroll
      for (int u = 0; u < 8; ++u) {
        uint4v wv = __builtin_nontemporal_load((const uint4v*)(mrow + u * 4));
        uint32_t nzb = (wv.x ? 1u : 0u) | (wv.y ? 2u : 0u) | (wv.z ? 4u : 0u) | (wv.w ? 8u : 0u);
        bits |= nzb << (u * 4);
      }
      mbits[row * 65 + wq] = bits;
    }
    for (int i = tid; i < QBLK * 65; i += NTH) cbuf[i] = 0.0f;
    if (tid < QBLK) lsum[tid] = 0.0f;
  }
  __syncthreads();

  // ---- Q as B-frag: lane holds Q[q0+c][.] ----
  short8 qB[2];
  {
    const float* qr = Qp + (size_t)(q0 + c) * D_;
    float4v x0 = *(const float4v*)(qr + g * 8);
    float4v x1 = *(const float4v*)(qr + g * 8 + 4);
    float4v y0 = *(const float4v*)(qr + 32 + g * 8);
    float4v y1 = *(const float4v*)(qr + 32 + g * 8 + 4);
    short8 f;
    f[0]=f2bf(x0.x); f[1]=f2bf(x0.y); f[2]=f2bf(x0.z); f[3]=f2bf(x0.w);
    f[4]=f2bf(x1.x); f[5]=f2bf(x1.y); f[6]=f2bf(x1.z); f[7]=f2bf(x1.w);
    qB[0] = f;
    f[0]=f2bf(y0.x); f[1]=f2bf(y0.y); f[2]=f2bf(y0.z); f[3]=f2bf(y0.w);
    f[4]=f2bf(y1.x); f[5]=f2bf(y1.y); f[6]=f2bf(y1.z); f[7]=f2bf(y1.w);
    qB[1] = f;
  }

  const uint32_t* mrowp = &mbits[c * 65 + (kslab0 >> 5)];
  float rsv = 0.0f;
  float4v cacc[4];
#pragma unroll
  for (int nd = 0; nd < 4; ++nd) cacc[nd] = (float4v){0.f, 0.f, 0.f, 0.f};

  // ---- single sweep: QK -> exp -> E to LDS -> PV (transient loads, TLP-hiding) ----
#pragma unroll 1
  for (int win = 0; win < NWIN; ++win) {
    const int kwin = kslab0 + win * 32;
    const int twin = win * 32;

    float4v acc0 = (float4v){0.f,0.f,0.f,0.f};
    float4v acc1 = (float4v){0.f,0.f,0.f,0.f};
    if (PREP) {
      const short* kr = Kbp + (size_t)(kwin + c) * D_ + g * 8;
      short8 a0 = *(const short8*)kr;
      short8 a1 = *(const short8*)(kr + 32);
      acc0 = __builtin_amdgcn_mfma_f32_16x16x32_bf16(a0, qB[0], acc0, 0, 0, 0);
      acc0 = __builtin_amdgcn_mfma_f32_16x16x32_bf16(a1, qB[1], acc0, 0, 0, 0);
      const short* kr1 = kr + 16 * D_;
      short8 a2 = *(const short8*)kr1;
      short8 a3 = *(const short8*)(kr1 + 32);
      acc1 = __builtin_amdgcn_mfma_f32_16x16x32_bf16(a2, qB[0], acc1, 0, 0, 0);
      acc1 = __builtin_amdgcn_mfma_f32_16x16x32_bf16(a3, qB[1], acc1, 0, 0, 0);
    } else {
      const float* kr = Kfp + (size_t)(kwin + c) * D_ + g * 8;
      const float* kr1 = kr + 16 * D_;
      short8 a0, a1, a2, a3;
#pragma unroll
      for (int e = 0; e < 8; ++e) {
        a0[e] = f2bf(kr[e]);  a1[e] = f2bf(kr[32 + e]);
        a2[e] = f2bf(kr1[e]); a3[e] = f2bf(kr1[32 + e]);
      }
      acc0 = __builtin_amdgcn_mfma_f32_16x16x32_bf16(a0, qB[0], acc0, 0, 0, 0);
      acc0 = __builtin_amdgcn_mfma_f32_16x16x32_bf16(a1, qB[1], acc0, 0, 0, 0);
      acc1 = __builtin_amdgcn_mfma_f32_16x16x32_bf16(a2, qB[0], acc1, 0, 0, 0);
      acc1 = __builtin_amdgcn_mfma_f32_16x16x32_bf16(a3, qB[1], acc1, 0, 0, 0);
    }

    // mask + exp (lane's q = c; k = kwin + nb*16 + 4g + r)
    const uint32_t mw = mrowp[win];
    float e0[4], e1[4];
#pragma unroll
    for (int r = 0; r < 4; ++r) {
      e0[r] = ((mw >> (4 * g + r)) & 1u)      ? 1.0f : __expf(acc0[r] * scale);
      e1[r] = ((mw >> (16 + 4 * g + r)) & 1u) ? 1.0f : __expf(acc1[r] * scale);
      rsv += e0[r] + e1[r];
    }
    uint2v lo, hi2;
    lo.x  = cvtpk(e0[0], e0[1]);  lo.y  = cvtpk(e0[2], e0[3]);
    hi2.x = cvtpk(e1[0], e1[1]);  hi2.y = cvtpk(e1[2], e1[3]);
    *(uint2v*)&etile[c * ETS + twin + 4 * g]      = lo;
    *(uint2v*)&etile[c * ETS + twin + 16 + 4 * g] = hi2;

    // PV B-frag from wave-private tile (lgkmcnt orders it)
    const short8 bfrag = *(const short8*)&etile[c * ETS + twin + g * 8];

    if (PREP) {
      const short* vb = VTp + (size_t)c * S_ + kwin + g * 8;
      short8 v0 = *(const short8*)vb;
      short8 v1 = *(const short8*)(vb + 16 * (size_t)S_);
      cacc[0] = __builtin_amdgcn_mfma_f32_16x16x32_bf16(v0, bfrag, cacc[0], 0, 0, 0);
      cacc[1] = __builtin_amdgcn_mfma_f32_16x16x32_bf16(v1, bfrag, cacc[1], 0, 0, 0);
      short8 v2 = *(const short8*)(vb + 32 * (size_t)S_);
      short8 v3 = *(const short8*)(vb + 48 * (size_t)S_);
      cacc[2] = __builtin_amdgcn_mfma_f32_16x16x32_bf16(v2, bfrag, cacc[2], 0, 0, 0);
      cacc[3] = __builtin_amdgcn_mfma_f32_16x16x32_bf16(v3, bfrag, cacc[3], 0, 0, 0);
    } else {
      const float* vc = Vfp + (size_t)(kwin + g * 8) * D_ + c;
#pragma unroll
      for (int nd = 0; nd < 4; ++nd) {
        short8 vv;
#pragma unroll
        for (int e = 0; e < 8; ++e) vv[e] = f2bf(vc[(size_t)e * D_ + nd * 16]);
        cacc[nd] = __builtin_amdgcn_mfma_f32_16x16x32_bf16(vv, bfrag, cacc[nd], 0, 0, 0);
      }
    }
  }

  // ---- reductions ----
  rsv += __shfl_xor(rsv, 16);
  rsv += __shfl_xor(rsv, 32);
  if (lane < 16) atomicAdd(&lsum[lane], rsv);
#pragma unroll
  for (int nd = 0; nd < 4; ++nd)
#pragma unroll
    for (int r = 0; r < 4; ++r)
      atomicAdd(&cbuf[c * 65 + nd * 16 + 4 * g + r], cacc[nd][r]);
  __syncthreads();

  if (tid < QBLK) linv[tid] = 1.0f / lsum[tid];
  __syncthreads();

  // ---- context write ----
  if (tid < QBLK * D_ / 4) {
    const int row = tid >> 4, d0 = (tid & 15) * 4;
    const float inv = linv[row];
    float4v cv;
    cv.x = cbuf[row * 65 + d0 + 0] * inv;
    cv.y = cbuf[row * 65 + d0 + 1] * inv;
    cv.z = cbuf[row * 65 + d0 + 2] * inv;
    cv.w = cbuf[row * 65 + d0 + 3] * inv;
    __builtin_nontemporal_store(cv, (float4v*)&outC[((size_t)(bh * S_ + q0 + row)) * D_ + d0]);
  }

  // ---- phase 2: full-line normalized attention stores (2 rows / instr) ----
  {
    const int rsel = lane >> 5;                 // 0..1
    const int colq = (lane & 31) * 4;           // 0..124
    float* abase = outA + ((size_t)(bh * S_ + q0)) * S_ + kslab0 + colq;
#pragma unroll
    for (int p = 0; p < 8; ++p) {
      const int r16 = p * 2 + rsel;
      const float inv = linv[r16];
      const uint2v ev = *(const uint2v*)&etile[r16 * ETS + colq];
      float4v av;
      av.x = bf2f(ev.x & 0xffff) * inv;
      av.y = bf2f(ev.x >> 16)    * inv;
      av.z = bf2f(ev.y & 0xffff) * inv;
      av.w = bf2f(ev.y >> 16)    * inv;
      __builtin_nontemporal_store(av, (float4v*)(abase + (size_t)r16 * S_));
    }
  }
}

extern "C" void kernel_launch(void* const* d_in, const int* in_sizes, int n_in,
                              void* d_out, int out_size, void* d_ws, size_t ws_size,
                              hipStream_t stream) {
  const float*   Q     = (const float*)d_in[0];
  const float*   K     = (const float*)d_in[1];
  const float*   V     = (const float*)d_in[2];
  const float*   scale = (const float*)d_in[3];
  const uint8_t* M     = (const uint8_t*)d_in[4];
  uint32_t* flag = (uint32_t*)d_ws;
  short* Kbf = (short*)((char*)d_ws + KBF_OFF);
  short* VT  = (short*)((char*)d_ws + VT_OFF);
  float* outC = (float*)d_out;
  float* outA = outC + (size_t)B_ * H_ * S_ * D_;

  hipMemsetAsync(flag, 0, 4, stream);
  detect_mask_dtype<<<dim3(1), dim3(256), 0, stream>>>(M, flag);

  const bool prep = ws_size >= VT_OFF + VT_BYTES;
  const int grid = B_ * H_ * (S_ / QBLK);       // 8192
  if (prep) {
    prep_k<<<dim3((B_ * H_ * S_ * D_) / (256 * 8)), dim3(256), 0, stream>>>(K, Kbf);
    prep_vt<<<dim3(B_ * H_ * (S_ / 64)), dim3(256), 0, stream>>>(V, VT);
    hipFuncSetAttribute(reinterpret_cast<const void*>(attn_fused<1>),
                        hipFuncAttributeMaxDynamicSharedMemorySize, SMEM_BYTES);
    attn_fused<1><<<dim3(grid), dim3(NTH), SMEM_BYTES, stream>>>(
        Q, K, V, scale, M, flag, Kbf, VT, outC, outA);
  } else {
    hipFuncSetAttribute(reinterpret_cast<const void*>(attn_fused<0>),
                        hipFuncAttributeMaxDynamicSharedMemorySize, SMEM_BYTES);
    attn_fused<0><<<dim3(grid), dim3(NTH), SMEM_BYTES, stream>>>(
        Q, K, V, scale, M, flag, Kbf, VT, outC, outA);
  }
}

// Round 16
// 1322.796 us; speedup vs baseline: 1.0523x; 1.0523x over previous
//
#include <hip/hip_runtime.h>
#include <stdint.h>

#define B_ 4
#define H_ 16
#define S_ 2048
#define D_ 64
#define NWIN 64                       /* 32-k windows, full S */
#define EBS 40                        /* ebounce row stride (shorts) */

typedef __attribute__((ext_vector_type(8))) short short8;
typedef __attribute__((ext_vector_type(4))) float float4v;
typedef __attribute__((ext_vector_type(4))) unsigned int uint4v;
typedef __attribute__((ext_vector_type(2))) unsigned int uint2v;

static __device__ __forceinline__ short f2bf(float f) {
  uint32_t u = __builtin_bit_cast(uint32_t, f);
  u = (u + 0x7FFFu + ((u >> 16) & 1u)) >> 16;   // RNE
  return (short)u;
}
static __device__ __forceinline__ float bf2f(uint32_t s) {
  return __builtin_bit_cast(float, s << 16);
}
static __device__ __forceinline__ uint32_t cvtpk(float lo, float hi) {
  uint32_t r;
  asm("v_cvt_pk_bf16_f32 %0, %1, %2" : "=v"(r) : "v"(lo), "v"(hi));
  return r;
}
static __device__ __forceinline__ uint32_t nz4(uint32_t d) {
  uint32_t x = (d & 0x7F7F7F7Fu) + 0x7F7F7F7Fu;
  x = (x | d) & 0x80808080u;
  return x >> 7;
}
static __device__ __forceinline__ uint32_t nib(uint32_t d) {
  return ((nz4(d) * 0x01020408u) >> 24) & 0xFu;
}

// workspace layout
#define LINV_OFF   ((size_t)64)
#define LINV_BYTES ((size_t)B_ * H_ * S_ * 4)            /* 512 KB */
#define KBF_OFF    (LINV_OFF + LINV_BYTES)
#define KBF_BYTES  ((size_t)B_ * H_ * S_ * D_ * 2)       /* 16 MB */
#define VT_OFF     (KBF_OFF + KBF_BYTES)
#define VT_BYTES   ((size_t)B_ * H_ * S_ * D_ * 2)       /* 16 MB */
#define MB_OFF     (VT_OFF + VT_BYTES)
#define MB_BYTES   ((size_t)B_ * H_ * S_ * 64 * 4)       /* 32 MB bitmap */

__global__ void detect_mask_dtype(const uint8_t* __restrict__ m, uint32_t* flag) {
  uint32_t a = 0, b = 0;
  for (int i = threadIdx.x; i < 65536; i += 256) {
    uint8_t x = m[i];
    if (i & 3) a |= x; else b |= x;
  }
  uint32_t bits = (a ? 1u : 0u) | (b ? 2u : 0u);
  if (bits) atomicOr(flag, bits);
}

__global__ __launch_bounds__(256) void prep_k(const float* __restrict__ K,
                                              short* __restrict__ Kbf) {
  size_t base = ((size_t)blockIdx.x * 256 + threadIdx.x) * 8;
  float4v a = __builtin_nontemporal_load((const float4v*)(K + base));
  float4v b = __builtin_nontemporal_load((const float4v*)(K + base + 4));
  short8 o;
  o[0]=f2bf(a.x); o[1]=f2bf(a.y); o[2]=f2bf(a.z); o[3]=f2bf(a.w);
  o[4]=f2bf(b.x); o[5]=f2bf(b.y); o[6]=f2bf(b.z); o[7]=f2bf(b.w);
  *(short8*)(Kbf + base) = o;
}

__global__ __launch_bounds__(256) void prep_vt(const float* __restrict__ V,
                                               short* __restrict__ VT) {
  __shared__ short tile[64][72];
  int bh = blockIdx.x >> 5, k0 = (blockIdx.x & 31) * 64;
  const float* src = V + ((size_t)bh * S_ + k0) * D_;
  int t = threadIdx.x;
  int r = t >> 2, c0 = (t & 3) * 16;
#pragma unroll
  for (int j = 0; j < 4; ++j) {
    float4v f = __builtin_nontemporal_load((const float4v*)(src + (size_t)r * D_ + c0 + j * 4));
    tile[r][c0 + j*4 + 0] = f2bf(f.x);
    tile[r][c0 + j*4 + 1] = f2bf(f.y);
    tile[r][c0 + j*4 + 2] = f2bf(f.z);
    tile[r][c0 + j*4 + 3] = f2bf(f.w);
  }
  __syncthreads();
  int d = t >> 2, ks0 = (t & 3) * 16;
  short* dst = VT + (size_t)bh * D_ * S_ + (size_t)d * S_ + k0 + ks0;
#pragma unroll
  for (int half = 0; half < 2; ++half) {
    short8 o;
#pragma unroll
    for (int i = 0; i < 8; ++i) o[i] = tile[ks0 + half * 8 + i][d];
    *(short8*)(dst + half * 8) = o;
  }
}

// =============== Pass 1: rowsums (-> linvG) + PV + context; bitmap -> ws ======
template <int PREP, int BM>
__global__ __launch_bounds__(512, 6) void k_sums(
    const float* __restrict__ Q, const float* __restrict__ K,
    const float* __restrict__ V, const float* __restrict__ scale_p,
    const uint8_t* __restrict__ M, const uint32_t* __restrict__ flag,
    const short* __restrict__ Kbf, const short* __restrict__ VT,
    float* __restrict__ linvG, uint32_t* __restrict__ mbitsG,
    float* __restrict__ outC)
{
  __shared__ uint32_t mbits[128 * 66];          // mask stride 65; ctx-alias stride 66
  __shared__ short kbuf[2][32 * 64];            // K window dbuf (XOR-swizzled)
  __shared__ short ebounce[8][16 * EBS];        // per-wave E bounce

  const int bx  = (blockIdx.x & 7) * 128 + (blockIdx.x >> 3);
  const int bh  = bx >> 4;
  const int q0  = (bx & 15) * 128;

  const int tid  = threadIdx.x;
  const int widx = tid >> 6;
  const int lane = tid & 63;
  const int g    = lane >> 4;
  const int c    = lane & 15;
  const int qrow = q0 + widx * 16 + c;

  const float scale = scale_p[0];
  const uint32_t fl = flag[0];

  const short* Kbp = Kbf + (size_t)bh * S_ * D_;
  const short* VTp = VT + (size_t)bh * D_ * S_;
  const float* Kfp = K + (size_t)bh * S_ * D_;
  const float* Vfp = V + (size_t)bh * S_ * D_;

  // ---- mask bitmap prologue: [128][2048] bits (stride 65) ----
  {
    const int row = tid >> 2;
    const int wq0 = (tid & 3) * 16;
    if (fl == 3u) {
      const uint8_t* mrow = M + ((size_t)(bh * S_ + q0 + row)) * S_ + wq0 * 32;
#pragma unroll
      for (int j = 0; j < 16; ++j) {
        uint4v a = __builtin_nontemporal_load((const uint4v*)(mrow + j * 32));
        uint4v b = __builtin_nontemporal_load((const uint4v*)(mrow + j * 32 + 16));
        mbits[row * 65 + wq0 + j] =
            nib(a.x) | (nib(a.y) << 4) | (nib(a.z) << 8)  | (nib(a.w) << 12)
          | (nib(b.x) << 16) | (nib(b.y) << 20) | (nib(b.z) << 24) | (nib(b.w) << 28);
      }
    } else {
      const uint32_t* mrow = (const uint32_t*)M + ((size_t)(bh * S_ + q0 + row)) * S_ + wq0 * 32;
#pragma unroll
      for (int j = 0; j < 16; ++j) {
        uint32_t bits = 0;
#pragma unroll
        for (int u = 0; u < 8; ++u) {
          uint4v wv = __builtin_nontemporal_load((const uint4v*)(mrow + j * 32 + u * 4));
          uint32_t nzb = (wv.x ? 1u : 0u) | (wv.y ? 2u : 0u) | (wv.z ? 4u : 0u) | (wv.w ? 8u : 0u);
          bits |= nzb << (u * 4);
        }
        mbits[row * 65 + wq0 + j] = bits;
      }
    }
    if (BM) {   // dump bitmap to ws for pass 2 (own rows, no sync needed)
      uint32_t* mg = mbitsG + ((size_t)(bh * S_ + q0 + row)) * 64 + wq0;
#pragma unroll
      for (int k4 = 0; k4 < 4; ++k4) {
        uint4v v;
        v.x = mbits[row * 65 + wq0 + k4 * 4 + 0];
        v.y = mbits[row * 65 + wq0 + k4 * 4 + 1];
        v.z = mbits[row * 65 + wq0 + k4 * 4 + 2];
        v.w = mbits[row * 65 + wq0 + k4 * 4 + 3];
        __builtin_nontemporal_store(v, (uint4v*)(mg + k4 * 4));
      }
    }
  }

  // ---- Q as B-frag: lane holds Q[qrow][.] ----
  short8 qB[2];
  {
    const float* qr = Q + ((size_t)(bh * S_ + qrow)) * D_;
    float4v x0 = *(const float4v*)(qr + g * 8);
    float4v x1 = *(const float4v*)(qr + g * 8 + 4);
    float4v y0 = *(const float4v*)(qr + 32 + g * 8);
    float4v y1 = *(const float4v*)(qr + 32 + g * 8 + 4);
    short8 f;
    f[0]=f2bf(x0.x); f[1]=f2bf(x0.y); f[2]=f2bf(x0.z); f[3]=f2bf(x0.w);
    f[4]=f2bf(x1.x); f[5]=f2bf(x1.y); f[6]=f2bf(x1.z); f[7]=f2bf(x1.w);
    qB[0] = f;
    f[0]=f2bf(y0.x); f[1]=f2bf(y0.y); f[2]=f2bf(y0.z); f[3]=f2bf(y0.w);
    f[4]=f2bf(y1.x); f[5]=f2bf(y1.y); f[6]=f2bf(y1.z); f[7]=f2bf(y1.w);
    qB[1] = f;
  }

  // ---- K staging (4 low waves, 16B/lane; XOR-swizzled LDS dest) ----
  const bool stager = (widx < 4);
  const int  sr = (widx << 3) + (lane >> 3);
  const int  sp = lane & 7;
  const int  sdst = sr * 64 + ((sp ^ (sr & 7)) << 3);
  short8  kreg;
  float4v kf0, kf1;
#define ISSUEK(W) do { if (stager) {                                           \
    if (PREP) kreg = *(const short8*)(Kbp + (size_t)((W) * 32 + sr) * 64 + sp * 8); \
    else { const float* s_ = Kfp + (size_t)((W) * 32 + sr) * 64 + sp * 8;      \
           kf0 = *(const float4v*)s_; kf1 = *(const float4v*)(s_ + 4); } } } while (0)
#define WRITEK(BUF) do { if (stager) {                                         \
    short8 o_;                                                                 \
    if (PREP) o_ = kreg;                                                       \
    else { o_[0]=f2bf(kf0.x); o_[1]=f2bf(kf0.y); o_[2]=f2bf(kf0.z); o_[3]=f2bf(kf0.w); \
           o_[4]=f2bf(kf1.x); o_[5]=f2bf(kf1.y); o_[6]=f2bf(kf1.z); o_[7]=f2bf(kf1.w); } \
    *(short8*)&kbuf[BUF][sdst] = o_; } } while (0)

  const int ka0 = ((g       ^ (c & 7)) << 3);
  const int ka1 = (((g + 4) ^ (c & 7)) << 3);
  const uint32_t* mrow = &mbits[(widx * 16 + c) * 65];

  ISSUEK(0); WRITEK(0); ISSUEK(1);
  __syncthreads();

  float rsv = 0.0f;
  float4v cacc[4];
#pragma unroll
  for (int nd = 0; nd < 4; ++nd) cacc[nd] = (float4v){0.f, 0.f, 0.f, 0.f};
  short* eb = &ebounce[widx][0];

#pragma unroll 1
  for (int w = 0; w < NWIN; ++w) {
    const int cur = w & 1;
    const int kwin = w * 32;

    short8 vA0, vA1, vA2, vA3;
    if (PREP) {
      const short* vb = VTp + (size_t)c * S_ + kwin + g * 8;
      vA0 = *(const short8*)vb;
      vA1 = *(const short8*)(vb + 16 * (size_t)S_);
      vA2 = *(const short8*)(vb + 32 * (size_t)S_);
      vA3 = *(const short8*)(vb + 48 * (size_t)S_);
    } else {
      const float* vc = Vfp + (size_t)(kwin + g * 8) * D_ + c;
#pragma unroll
      for (int e = 0; e < 8; ++e) {
        vA0[e] = f2bf(vc[(size_t)e * D_]);
        vA1[e] = f2bf(vc[(size_t)e * D_ + 16]);
        vA2[e] = f2bf(vc[(size_t)e * D_ + 32]);
        vA3[e] = f2bf(vc[(size_t)e * D_ + 48]);
      }
    }

    const short* kb = &kbuf[cur][0];
    short8 a0 = *(const short8*)(kb + c * 64 + ka0);
    short8 a1 = *(const short8*)(kb + c * 64 + ka1);
    short8 a2 = *(const short8*)(kb + (c + 16) * 64 + ka0);
    short8 a3 = *(const short8*)(kb + (c + 16) * 64 + ka1);

    float4v acc0 = (float4v){0.f,0.f,0.f,0.f};
    float4v acc1 = (float4v){0.f,0.f,0.f,0.f};
    acc0 = __builtin_amdgcn_mfma_f32_16x16x32_bf16(a0, qB[0], acc0, 0, 0, 0);
    acc0 = __builtin_amdgcn_mfma_f32_16x16x32_bf16(a1, qB[1], acc0, 0, 0, 0);
    acc1 = __builtin_amdgcn_mfma_f32_16x16x32_bf16(a2, qB[0], acc1, 0, 0, 0);
    acc1 = __builtin_amdgcn_mfma_f32_16x16x32_bf16(a3, qB[1], acc1, 0, 0, 0);

    const uint32_t mw = mrow[w];
    float e0[4], e1[4];
#pragma unroll
    for (int r = 0; r < 4; ++r) {
      e0[r] = ((mw >> (4 * g + r)) & 1u)      ? 1.0f : __expf(acc0[r] * scale);
      e1[r] = ((mw >> (16 + 4 * g + r)) & 1u) ? 1.0f : __expf(acc1[r] * scale);
      rsv += e0[r] + e1[r];
    }
    uint2v lo, hi2;
    lo.x  = cvtpk(e0[0], e0[1]);  lo.y  = cvtpk(e0[2], e0[3]);
    hi2.x = cvtpk(e1[0], e1[1]);  hi2.y = cvtpk(e1[2], e1[3]);
    *(uint2v*)&eb[c * EBS + 4 * g]      = lo;
    *(uint2v*)&eb[c * EBS + 16 + 4 * g] = hi2;
    const short8 bfrag = *(const short8*)&eb[c * EBS + g * 8];

    cacc[0] = __builtin_amdgcn_mfma_f32_16x16x32_bf16(vA0, bfrag, cacc[0], 0, 0, 0);
    cacc[1] = __builtin_amdgcn_mfma_f32_16x16x32_bf16(vA1, bfrag, cacc[1], 0, 0, 0);
    cacc[2] = __builtin_amdgcn_mfma_f32_16x16x32_bf16(vA2, bfrag, cacc[2], 0, 0, 0);
    cacc[3] = __builtin_amdgcn_mfma_f32_16x16x32_bf16(vA3, bfrag, cacc[3], 0, 0, 0);

    if (w + 1 < NWIN) {
      WRITEK(cur ^ 1);
      if (w + 2 < NWIN) ISSUEK(w + 2);
      __syncthreads();
    }
  }
#undef ISSUEK
#undef WRITEK

  rsv += __shfl_xor(rsv, 16);
  rsv += __shfl_xor(rsv, 32);
  const float linv = 1.0f / rsv;
  if (g == 0) linvG[(size_t)bh * S_ + qrow] = linv;
  __syncthreads();                              // mask dead; alias mbits for ctx

  // ---- context epilogue: normalize cacc, LDS transpose (stride 66), store ----
  {
    float* cst = (float*)mbits;                 // [128][66] floats
#pragma unroll
    for (int nd = 0; nd < 4; ++nd) {
      float4v v;
#pragma unroll
      for (int r = 0; r < 4; ++r) v[r] = cacc[nd][r] * linv;
      *(float4v*)&cst[(widx * 16 + c) * 66 + nd * 16 + 4 * g] = v;
    }
    __syncthreads();
    const int qq = tid >> 2, ch = tid & 3;
    const float* src = &cst[qq * 66 + ch * 16];
    float* dst = outC + ((size_t)(bh * S_ + q0 + qq)) * D_ + ch * 16;
    float4v c0 = *(const float4v*)src;
    float4v c1 = *(const float4v*)(src + 4);
    float4v c2 = *(const float4v*)(src + 8);
    float4v c3 = *(const float4v*)(src + 12);
    __builtin_nontemporal_store(c0, (float4v*)dst);
    __builtin_nontemporal_store(c1, (float4v*)(dst + 4));
    __builtin_nontemporal_store(c2, (float4v*)(dst + 8));
    __builtin_nontemporal_store(c3, (float4v*)(dst + 12));
  }
}

// =============== Pass 2: QK -> exp -> xlinv -> full-line nt stores ===========
template <int PREP, int BM>
__global__ __launch_bounds__(256, 7) void k_store(
    const float* __restrict__ Q, const float* __restrict__ K,
    const float* __restrict__ scale_p, const uint8_t* __restrict__ M,
    const uint32_t* __restrict__ flag, const short* __restrict__ Kbf,
    const float* __restrict__ linvG, const uint32_t* __restrict__ mbitsG,
    float* __restrict__ outA)
{
  __shared__ uint32_t mbits2[64 * 65];
  __shared__ short eb2[4][16 * EBS];

  const int bx  = (blockIdx.x & 7) * 256 + (blockIdx.x >> 3);
  const int bh  = bx >> 5;                      // 32 blocks of 64 q-rows per bh
  const int q0  = (bx & 31) * 64;

  const int tid  = threadIdx.x;
  const int wv   = tid >> 6;                    // 0..3
  const int lane = tid & 63;
  const int g    = lane >> 4;
  const int c    = lane & 15;
  const int qrow = q0 + wv * 16 + c;

  const float scale = scale_p[0];
  const uint32_t fl = flag[0];

  const short* Kbp = Kbf + (size_t)bh * S_ * D_;
  const float* Kfp = K + (size_t)bh * S_ * D_;

  // ---- bitmap prologue: 64 rows ----
  {
    const int row = tid >> 2;                   // 0..63
    const int wq0 = (tid & 3) * 16;
    if (BM) {
      const uint32_t* mg = mbitsG + ((size_t)(bh * S_ + q0 + row)) * 64 + wq0;
#pragma unroll
      for (int k4 = 0; k4 < 4; ++k4) {
        uint4v v = __builtin_nontemporal_load((const uint4v*)(mg + k4 * 4));
        mbits2[row * 65 + wq0 + k4 * 4 + 0] = v.x;
        mbits2[row * 65 + wq0 + k4 * 4 + 1] = v.y;
        mbits2[row * 65 + wq0 + k4 * 4 + 2] = v.z;
        mbits2[row * 65 + wq0 + k4 * 4 + 3] = v.w;
      }
    } else if (fl == 3u) {
      const uint8_t* mrow = M + ((size_t)(bh * S_ + q0 + row)) * S_ + wq0 * 32;
#pragma unroll
      for (int j = 0; j < 16; ++j) {
        uint4v a = __builtin_nontemporal_load((const uint4v*)(mrow + j * 32));
        uint4v b = __builtin_nontemporal_load((const uint4v*)(mrow + j * 32 + 16));
        mbits2[row * 65 + wq0 + j] =
            nib(a.x) | (nib(a.y) << 4) | (nib(a.z) << 8)  | (nib(a.w) << 12)
          | (nib(b.x) << 16) | (nib(b.y) << 20) | (nib(b.z) << 24) | (nib(b.w) << 28);
      }
    } else {
      const uint32_t* mrow = (const uint32_t*)M + ((size_t)(bh * S_ + q0 + row)) * S_ + wq0 * 32;
#pragma unroll
      for (int j = 0; j < 16; ++j) {
        uint32_t bits = 0;
#pragma unroll
        for (int u = 0; u < 8; ++u) {
          uint4v wvv = __builtin_nontemporal_load((const uint4v*)(mrow + j * 32 + u * 4));
          uint32_t nzb = (wvv.x ? 1u : 0u) | (wvv.y ? 2u : 0u) | (wvv.z ? 4u : 0u) | (wvv.w ? 8u : 0u);
          bits |= nzb << (u * 4);
        }
        mbits2[row * 65 + wq0 + j] = bits;
      }
    }
  }

  // ---- Q as B-frag + per-row inverse sum (register) ----
  short8 qB[2];
  {
    const float* qr = Q + ((size_t)(bh * S_ + qrow)) * D_;
    float4v x0 = *(const float4v*)(qr + g * 8);
    float4v x1 = *(const float4v*)(qr + g * 8 + 4);
    float4v y0 = *(const float4v*)(qr + 32 + g * 8);
    float4v y1 = *(const float4v*)(qr + 32 + g * 8 + 4);
    short8 f;
    f[0]=f2bf(x0.x); f[1]=f2bf(x0.y); f[2]=f2bf(x0.z); f[3]=f2bf(x0.w);
    f[4]=f2bf(x1.x); f[5]=f2bf(x1.y); f[6]=f2bf(x1.z); f[7]=f2bf(x1.w);
    qB[0] = f;
    f[0]=f2bf(y0.x); f[1]=f2bf(y0.y); f[2]=f2bf(y0.z); f[3]=f2bf(y0.w);
    f[4]=f2bf(y1.x); f[5]=f2bf(y1.y); f[6]=f2bf(y1.z); f[7]=f2bf(y1.w);
    qB[1] = f;
  }
  const float linvq = linvG[(size_t)bh * S_ + qrow];
  __syncthreads();

  const uint32_t* mrow = &mbits2[(wv * 16 + c) * 65];
  short* eb = &eb2[wv][0];
  const int srow = lane >> 3;                   // 0..7
  const int scol = lane & 7;                    // 4-float chunk
  float* arow0 = outA + ((size_t)(bh * S_ + q0 + wv * 16 + srow)) * S_ + scol * 4;
  float* arow1 = outA + ((size_t)(bh * S_ + q0 + wv * 16 + srow + 8)) * S_ + scol * 4;

#pragma unroll 1
  for (int w = 0; w < NWIN; ++w) {
    const int kwin = w * 32;

    float4v acc0 = (float4v){0.f,0.f,0.f,0.f};
    float4v acc1 = (float4v){0.f,0.f,0.f,0.f};
    if (PREP) {
      const short* kr = Kbp + (size_t)(kwin + c) * D_ + g * 8;
      short8 a0 = *(const short8*)kr;
      short8 a1 = *(const short8*)(kr + 32);
      const short* kr1 = kr + 16 * D_;
      short8 a2 = *(const short8*)kr1;
      short8 a3 = *(const short8*)(kr1 + 32);
      acc0 = __builtin_amdgcn_mfma_f32_16x16x32_bf16(a0, qB[0], acc0, 0, 0, 0);
      acc0 = __builtin_amdgcn_mfma_f32_16x16x32_bf16(a1, qB[1], acc0, 0, 0, 0);
      acc1 = __builtin_amdgcn_mfma_f32_16x16x32_bf16(a2, qB[0], acc1, 0, 0, 0);
      acc1 = __builtin_amdgcn_mfma_f32_16x16x32_bf16(a3, qB[1], acc1, 0, 0, 0);
    } else {
      const float* kr = Kfp + (size_t)(kwin + c) * D_ + g * 8;
      const float* kr1 = kr + 16 * D_;
      short8 a0, a1, a2, a3;
#pragma unroll
      for (int e = 0; e < 8; ++e) {
        a0[e] = f2bf(kr[e]);  a1[e] = f2bf(kr[32 + e]);
        a2[e] = f2bf(kr1[e]); a3[e] = f2bf(kr1[32 + e]);
      }
      acc0 = __builtin_amdgcn_mfma_f32_16x16x32_bf16(a0, qB[0], acc0, 0, 0, 0);
      acc0 = __builtin_amdgcn_mfma_f32_16x16x32_bf16(a1, qB[1], acc0, 0, 0, 0);
      acc1 = __builtin_amdgcn_mfma_f32_16x16x32_bf16(a2, qB[0], acc1, 0, 0, 0);
      acc1 = __builtin_amdgcn_mfma_f32_16x16x32_bf16(a3, qB[1], acc1, 0, 0, 0);
    }

    const uint32_t mw = mrow[w];
    float n0[4], n1[4];
#pragma unroll
    for (int r = 0; r < 4; ++r) {
      n0[r] = (((mw >> (4 * g + r)) & 1u)      ? 1.0f : __expf(acc0[r] * scale)) * linvq;
      n1[r] = (((mw >> (16 + 4 * g + r)) & 1u) ? 1.0f : __expf(acc1[r] * scale)) * linvq;
    }
    uint2v lo, hi2;
    lo.x  = cvtpk(n0[0], n0[1]);  lo.y  = cvtpk(n0[2], n0[3]);
    hi2.x = cvtpk(n1[0], n1[1]);  hi2.y = cvtpk(n1[2], n1[3]);
    *(uint2v*)&eb[c * EBS + 4 * g]      = lo;
    *(uint2v*)&eb[c * EBS + 16 + 4 * g] = hi2;

    // full-128B-line stores: 8 rows per instruction (wave-private tile read)
    const uint2v ev0 = *(const uint2v*)&eb[srow * EBS + scol * 4];
    const uint2v ev1 = *(const uint2v*)&eb[(srow + 8) * EBS + scol * 4];
    float4v s0, s1;
    s0.x = bf2f(ev0.x & 0xffff); s0.y = bf2f(ev0.x >> 16);
    s0.z = bf2f(ev0.y & 0xffff); s0.w = bf2f(ev0.y >> 16);
    s1.x = bf2f(ev1.x & 0xffff); s1.y = bf2f(ev1.x >> 16);
    s1.z = bf2f(ev1.y & 0xffff); s1.w = bf2f(ev1.y >> 16);
    __builtin_nontemporal_store(s0, (float4v*)(arow0 + kwin));
    __builtin_nontemporal_store(s1, (float4v*)(arow1 + kwin));
  }
}

extern "C" void kernel_launch(void* const* d_in, const int* in_sizes, int n_in,
                              void* d_out, int out_size, void* d_ws, size_t ws_size,
                              hipStream_t stream) {
  const float*   Q     = (const float*)d_in[0];
  const float*   K     = (const float*)d_in[1];
  const float*   V     = (const float*)d_in[2];
  const float*   scale = (const float*)d_in[3];
  const uint8_t* M     = (const uint8_t*)d_in[4];
  uint32_t* flag  = (uint32_t*)d_ws;
  float*    linvG = (float*)((char*)d_ws + LINV_OFF);
  short*    Kbf   = (short*)((char*)d_ws + KBF_OFF);
  short*    VT    = (short*)((char*)d_ws + VT_OFF);
  uint32_t* mbG   = (uint32_t*)((char*)d_ws + MB_OFF);
  float* outC = (float*)d_out;
  float* outA = outC + (size_t)B_ * H_ * S_ * D_;

  hipMemsetAsync(flag, 0, 4, stream);
  detect_mask_dtype<<<dim3(1), dim3(256), 0, stream>>>(M, flag);

  const bool prep = ws_size >= VT_OFF + VT_BYTES;
  const bool bm   = ws_size >= MB_OFF + MB_BYTES;
  const int grid1 = B_ * H_ * (S_ / 128);       // 1024
  const int grid2 = B_ * H_ * (S_ / 64);        // 2048

  if (prep) {
    prep_k<<<dim3((B_ * H_ * S_ * D_) / (256 * 8)), dim3(256), 0, stream>>>(K, Kbf);
    prep_vt<<<dim3(B_ * H_ * (S_ / 64)), dim3(256), 0, stream>>>(V, VT);
    if (bm) {
      k_sums<1, 1><<<dim3(grid1), dim3(512), 0, stream>>>(
          Q, K, V, scale, M, flag, Kbf, VT, linvG, mbG, outC);
      k_store<1, 1><<<dim3(grid2), dim3(256), 0, stream>>>(
          Q, K, scale, M, flag, Kbf, linvG, mbG, outA);
    } else {
      k_sums<1, 0><<<dim3(grid1), dim3(512), 0, stream>>>(
          Q, K, V, scale, M, flag, Kbf, VT, linvG, mbG, outC);
      k_store<1, 0><<<dim3(grid2), dim3(256), 0, stream>>>(
          Q, K, scale, M, flag, Kbf, linvG, mbG, outA);
    }
  } else {
    k_sums<0, 0><<<dim3(grid1), dim3(512), 0, stream>>>(
        Q, K, V, scale, M, flag, Kbf, VT, linvG, mbG, outC);
    k_store<0, 0><<<dim3(grid2), dim3(256), 0, stream>>>(
        Q, K, scale, M, flag, Kbf, linvG, mbG, outA);
  }
}

// Round 17
// 1197.403 us; speedup vs baseline: 1.1625x; 1.1047x over previous
//
#include <hip/hip_runtime.h>
#include <stdint.h>

#define B_ 4
#define H_ 16
#define S_ 2048
#define D_ 64
#define NWIN 64                       /* 32-k windows, full S */
#define EBS 40                        /* ebounce row stride (shorts) */
#define VBS 40                        /* vbuf row stride (shorts) */

typedef __attribute__((ext_vector_type(8))) short short8;
typedef __attribute__((ext_vector_type(4))) float float4v;
typedef __attribute__((ext_vector_type(4))) unsigned int uint4v;
typedef __attribute__((ext_vector_type(2))) unsigned int uint2v;

static __device__ __forceinline__ short f2bf(float f) {
  uint32_t u = __builtin_bit_cast(uint32_t, f);
  u = (u + 0x7FFFu + ((u >> 16) & 1u)) >> 16;   // RNE
  return (short)u;
}
static __device__ __forceinline__ float bf2f(uint32_t s) {
  return __builtin_bit_cast(float, s << 16);
}
static __device__ __forceinline__ uint32_t cvtpk(float lo, float hi) {
  uint32_t r;
  asm("v_cvt_pk_bf16_f32 %0, %1, %2" : "=v"(r) : "v"(lo), "v"(hi));
  return r;
}
static __device__ __forceinline__ uint32_t nz4(uint32_t d) {
  uint32_t x = (d & 0x7F7F7F7Fu) + 0x7F7F7F7Fu;
  x = (x | d) & 0x80808080u;
  return x >> 7;
}
static __device__ __forceinline__ uint32_t nib(uint32_t d) {
  return ((nz4(d) * 0x01020408u) >> 24) & 0xFu;
}

// workspace layout
#define LINV_OFF   ((size_t)64)
#define LINV_BYTES ((size_t)B_ * H_ * S_ * 4)            /* 512 KB */
#define KBF_OFF    (LINV_OFF + LINV_BYTES)
#define KBF_BYTES  ((size_t)B_ * H_ * S_ * D_ * 2)       /* 16 MB */
#define VT_OFF     (KBF_OFF + KBF_BYTES)
#define VT_BYTES   ((size_t)B_ * H_ * S_ * D_ * 2)       /* 16 MB */
#define MB_OFF     (VT_OFF + VT_BYTES)
#define MB_BYTES   ((size_t)B_ * H_ * S_ * 64 * 4)       /* 32 MB bitmap */

__global__ void detect_mask_dtype(const uint8_t* __restrict__ m, uint32_t* flag) {
  uint32_t a = 0, b = 0;
  for (int i = threadIdx.x; i < 65536; i += 256) {
    uint8_t x = m[i];
    if (i & 3) a |= x; else b |= x;
  }
  uint32_t bits = (a ? 1u : 0u) | (b ? 2u : 0u);
  if (bits) atomicOr(flag, bits);
}

__global__ __launch_bounds__(256) void prep_k(const float* __restrict__ K,
                                              short* __restrict__ Kbf) {
  size_t base = ((size_t)blockIdx.x * 256 + threadIdx.x) * 8;
  float4v a = __builtin_nontemporal_load((const float4v*)(K + base));
  float4v b = __builtin_nontemporal_load((const float4v*)(K + base + 4));
  short8 o;
  o[0]=f2bf(a.x); o[1]=f2bf(a.y); o[2]=f2bf(a.z); o[3]=f2bf(a.w);
  o[4]=f2bf(b.x); o[5]=f2bf(b.y); o[6]=f2bf(b.z); o[7]=f2bf(b.w);
  *(short8*)(Kbf + base) = o;
}

__global__ __launch_bounds__(256) void prep_vt(const float* __restrict__ V,
                                               short* __restrict__ VT) {
  __shared__ short tile[64][72];
  int bh = blockIdx.x >> 5, k0 = (blockIdx.x & 31) * 64;
  const float* src = V + ((size_t)bh * S_ + k0) * D_;
  int t = threadIdx.x;
  int r = t >> 2, c0 = (t & 3) * 16;
#pragma unroll
  for (int j = 0; j < 4; ++j) {
    float4v f = __builtin_nontemporal_load((const float4v*)(src + (size_t)r * D_ + c0 + j * 4));
    tile[r][c0 + j*4 + 0] = f2bf(f.x);
    tile[r][c0 + j*4 + 1] = f2bf(f.y);
    tile[r][c0 + j*4 + 2] = f2bf(f.z);
    tile[r][c0 + j*4 + 3] = f2bf(f.w);
  }
  __syncthreads();
  int d = t >> 2, ks0 = (t & 3) * 16;
  short* dst = VT + (size_t)bh * D_ * S_ + (size_t)d * S_ + k0 + ks0;
#pragma unroll
  for (int half = 0; half < 2; ++half) {
    short8 o;
#pragma unroll
    for (int i = 0; i < 8; ++i) o[i] = tile[ks0 + half * 8 + i][d];
    *(short8*)(dst + half * 8) = o;
  }
}

// === Pass 1: rowsums (-> linvG) + PV + context; K AND V LDS-relayed ==========
template <int PREP, int BM>
__global__ __launch_bounds__(512, 6) void k_sums(
    const float* __restrict__ Q, const float* __restrict__ K,
    const float* __restrict__ V, const float* __restrict__ scale_p,
    const uint8_t* __restrict__ M, const uint32_t* __restrict__ flag,
    const short* __restrict__ Kbf, const short* __restrict__ VT,
    float* __restrict__ linvG, uint32_t* __restrict__ mbitsG,
    float* __restrict__ outC)
{
  __shared__ uint32_t mbits[128 * 66];          // mask stride 65; ctx-alias stride 66
  __shared__ short kbuf[2][32 * 64];            // K window dbuf (XOR-swizzled)
  __shared__ short vbuf[2][64 * VBS];           // V window dbuf [d][k] (padded)
  __shared__ short ebounce[8][16 * EBS];        // per-wave E bounce

  const int bx  = (blockIdx.x & 7) * 128 + (blockIdx.x >> 3);
  const int bh  = bx >> 4;
  const int q0  = (bx & 15) * 128;

  const int tid  = threadIdx.x;
  const int widx = tid >> 6;
  const int lane = tid & 63;
  const int g    = lane >> 4;
  const int c    = lane & 15;
  const int qrow = q0 + widx * 16 + c;

  const float scale = scale_p[0];
  const uint32_t fl = flag[0];

  const short* Kbp = Kbf + (size_t)bh * S_ * D_;
  const short* VTp = VT + (size_t)bh * D_ * S_;
  const float* Kfp = K + (size_t)bh * S_ * D_;
  const float* Vfp = V + (size_t)bh * S_ * D_;

  // ---- mask bitmap prologue: [128][2048] bits (stride 65) ----
  {
    const int row = tid >> 2;
    const int wq0 = (tid & 3) * 16;
    if (fl == 3u) {
      const uint8_t* mrow = M + ((size_t)(bh * S_ + q0 + row)) * S_ + wq0 * 32;
#pragma unroll
      for (int j = 0; j < 16; ++j) {
        uint4v a = __builtin_nontemporal_load((const uint4v*)(mrow + j * 32));
        uint4v b = __builtin_nontemporal_load((const uint4v*)(mrow + j * 32 + 16));
        mbits[row * 65 + wq0 + j] =
            nib(a.x) | (nib(a.y) << 4) | (nib(a.z) << 8)  | (nib(a.w) << 12)
          | (nib(b.x) << 16) | (nib(b.y) << 20) | (nib(b.z) << 24) | (nib(b.w) << 28);
      }
    } else {
      const uint32_t* mrow = (const uint32_t*)M + ((size_t)(bh * S_ + q0 + row)) * S_ + wq0 * 32;
#pragma unroll
      for (int j = 0; j < 16; ++j) {
        uint32_t bits = 0;
#pragma unroll
        for (int u = 0; u < 8; ++u) {
          uint4v wv = __builtin_nontemporal_load((const uint4v*)(mrow + j * 32 + u * 4));
          uint32_t nzb = (wv.x ? 1u : 0u) | (wv.y ? 2u : 0u) | (wv.z ? 4u : 0u) | (wv.w ? 8u : 0u);
          bits |= nzb << (u * 4);
        }
        mbits[row * 65 + wq0 + j] = bits;
      }
    }
    if (BM) {   // dump bitmap to ws for pass 2 (own rows, no sync needed)
      uint32_t* mg = mbitsG + ((size_t)(bh * S_ + q0 + row)) * 64 + wq0;
#pragma unroll
      for (int k4 = 0; k4 < 4; ++k4) {
        uint4v v;
        v.x = mbits[row * 65 + wq0 + k4 * 4 + 0];
        v.y = mbits[row * 65 + wq0 + k4 * 4 + 1];
        v.z = mbits[row * 65 + wq0 + k4 * 4 + 2];
        v.w = mbits[row * 65 + wq0 + k4 * 4 + 3];
        __builtin_nontemporal_store(v, (uint4v*)(mg + k4 * 4));
      }
    }
  }

  // ---- Q as B-frag: lane holds Q[qrow][.] ----
  short8 qB[2];
  {
    const float* qr = Q + ((size_t)(bh * S_ + qrow)) * D_;
    float4v x0 = *(const float4v*)(qr + g * 8);
    float4v x1 = *(const float4v*)(qr + g * 8 + 4);
    float4v y0 = *(const float4v*)(qr + 32 + g * 8);
    float4v y1 = *(const float4v*)(qr + 32 + g * 8 + 4);
    short8 f;
    f[0]=f2bf(x0.x); f[1]=f2bf(x0.y); f[2]=f2bf(x0.z); f[3]=f2bf(x0.w);
    f[4]=f2bf(x1.x); f[5]=f2bf(x1.y); f[6]=f2bf(x1.z); f[7]=f2bf(x1.w);
    qB[0] = f;
    f[0]=f2bf(y0.x); f[1]=f2bf(y0.y); f[2]=f2bf(y0.z); f[3]=f2bf(y0.w);
    f[4]=f2bf(y1.x); f[5]=f2bf(y1.y); f[6]=f2bf(y1.z); f[7]=f2bf(y1.w);
    qB[1] = f;
  }

  // ---- staging: waves 0-3 relay K (XOR-swizzled), waves 4-7 relay V ----
  const bool kstager = (widx < 4);
  const bool vstager = (widx >= 4) && (PREP != 0);
  const int  sr = (widx << 3) + (lane >> 3);    // K tile row 0..31 (widx<4)
  const int  sp = lane & 7;                     // K chunk 0..7
  const int  sdst = sr * 64 + ((sp ^ (sr & 7)) << 3);
  const int  vr = ((widx - 4) << 4) + (lane >> 2);  // V d-row 0..63 (widx>=4)
  const int  vp = lane & 3;                     // V chunk 0..3 (8 shorts each)
  short8  kreg, vreg;
  float4v kf0, kf1;
#define ISSUE(W) do {                                                          \
    if (kstager) {                                                             \
      if (PREP) kreg = *(const short8*)(Kbp + (size_t)((W) * 32 + sr) * 64 + sp * 8); \
      else { const float* s_ = Kfp + (size_t)((W) * 32 + sr) * 64 + sp * 8;    \
             kf0 = *(const float4v*)s_; kf1 = *(const float4v*)(s_ + 4); }     \
    } else if (vstager) {                                                      \
      vreg = *(const short8*)(VTp + (size_t)vr * S_ + (W) * 32 + vp * 8);      \
    } } while (0)
#define WRITE(BUF) do {                                                        \
    if (kstager) {                                                             \
      short8 o_;                                                               \
      if (PREP) o_ = kreg;                                                     \
      else { o_[0]=f2bf(kf0.x); o_[1]=f2bf(kf0.y); o_[2]=f2bf(kf0.z); o_[3]=f2bf(kf0.w); \
             o_[4]=f2bf(kf1.x); o_[5]=f2bf(kf1.y); o_[6]=f2bf(kf1.z); o_[7]=f2bf(kf1.w); } \
      *(short8*)&kbuf[BUF][sdst] = o_;                                         \
    } else if (vstager) {                                                      \
      *(short8*)&vbuf[BUF][vr * VBS + vp * 8] = vreg;                          \
    } } while (0)

  const int ka0 = ((g       ^ (c & 7)) << 3);
  const int ka1 = (((g + 4) ^ (c & 7)) << 3);
  const uint32_t* mrow = &mbits[(widx * 16 + c) * 65];

  ISSUE(0); WRITE(0); ISSUE(1);
  __syncthreads();

  float rsv = 0.0f;
  float4v cacc[4];
#pragma unroll
  for (int nd = 0; nd < 4; ++nd) cacc[nd] = (float4v){0.f, 0.f, 0.f, 0.f};
  short* eb = &ebounce[widx][0];

#pragma unroll 1
  for (int w = 0; w < NWIN; ++w) {
    const int cur = w & 1;
    const int kwin = w * 32;

    short8 vA0, vA1, vA2, vA3;
    if (PREP) {
      const short* vb = &vbuf[cur][0];
      vA0 = *(const short8*)(vb + (size_t)(c)      * VBS + g * 8);
      vA1 = *(const short8*)(vb + (size_t)(16 + c) * VBS + g * 8);
      vA2 = *(const short8*)(vb + (size_t)(32 + c) * VBS + g * 8);
      vA3 = *(const short8*)(vb + (size_t)(48 + c) * VBS + g * 8);
    } else {
      const float* vc = Vfp + (size_t)(kwin + g * 8) * D_ + c;
#pragma unroll
      for (int e = 0; e < 8; ++e) {
        vA0[e] = f2bf(vc[(size_t)e * D_]);
        vA1[e] = f2bf(vc[(size_t)e * D_ + 16]);
        vA2[e] = f2bf(vc[(size_t)e * D_ + 32]);
        vA3[e] = f2bf(vc[(size_t)e * D_ + 48]);
      }
    }

    const short* kb = &kbuf[cur][0];
    short8 a0 = *(const short8*)(kb + c * 64 + ka0);
    short8 a1 = *(const short8*)(kb + c * 64 + ka1);
    short8 a2 = *(const short8*)(kb + (c + 16) * 64 + ka0);
    short8 a3 = *(const short8*)(kb + (c + 16) * 64 + ka1);

    float4v acc0 = (float4v){0.f,0.f,0.f,0.f};
    float4v acc1 = (float4v){0.f,0.f,0.f,0.f};
    acc0 = __builtin_amdgcn_mfma_f32_16x16x32_bf16(a0, qB[0], acc0, 0, 0, 0);
    acc0 = __builtin_amdgcn_mfma_f32_16x16x32_bf16(a1, qB[1], acc0, 0, 0, 0);
    acc1 = __builtin_amdgcn_mfma_f32_16x16x32_bf16(a2, qB[0], acc1, 0, 0, 0);
    acc1 = __builtin_amdgcn_mfma_f32_16x16x32_bf16(a3, qB[1], acc1, 0, 0, 0);

    const uint32_t mw = mrow[w];
    float e0[4], e1[4];
#pragma unroll
    for (int r = 0; r < 4; ++r) {
      e0[r] = ((mw >> (4 * g + r)) & 1u)      ? 1.0f : __expf(acc0[r] * scale);
      e1[r] = ((mw >> (16 + 4 * g + r)) & 1u) ? 1.0f : __expf(acc1[r] * scale);
      rsv += e0[r] + e1[r];
    }
    uint2v lo, hi2;
    lo.x  = cvtpk(e0[0], e0[1]);  lo.y  = cvtpk(e0[2], e0[3]);
    hi2.x = cvtpk(e1[0], e1[1]);  hi2.y = cvtpk(e1[2], e1[3]);
    *(uint2v*)&eb[c * EBS + 4 * g]      = lo;
    *(uint2v*)&eb[c * EBS + 16 + 4 * g] = hi2;
    const short8 bfrag = *(const short8*)&eb[c * EBS + g * 8];

    cacc[0] = __builtin_amdgcn_mfma_f32_16x16x32_bf16(vA0, bfrag, cacc[0], 0, 0, 0);
    cacc[1] = __builtin_amdgcn_mfma_f32_16x16x32_bf16(vA1, bfrag, cacc[1], 0, 0, 0);
    cacc[2] = __builtin_amdgcn_mfma_f32_16x16x32_bf16(vA2, bfrag, cacc[2], 0, 0, 0);
    cacc[3] = __builtin_amdgcn_mfma_f32_16x16x32_bf16(vA3, bfrag, cacc[3], 0, 0, 0);

    if (w + 1 < NWIN) {
      WRITE(cur ^ 1);
      if (w + 2 < NWIN) ISSUE(w + 2);
      __syncthreads();
    }
  }
#undef ISSUE
#undef WRITE

  rsv += __shfl_xor(rsv, 16);
  rsv += __shfl_xor(rsv, 32);
  const float linv = 1.0f / rsv;
  if (g == 0) linvG[(size_t)bh * S_ + qrow] = linv;
  __syncthreads();                              // mask dead; alias mbits for ctx

  // ---- context epilogue: normalize cacc, LDS transpose (stride 66), store ----
  {
    float* cst = (float*)mbits;                 // [128][66] floats
#pragma unroll
    for (int nd = 0; nd < 4; ++nd) {
      float4v v;
#pragma unroll
      for (int r = 0; r < 4; ++r) v[r] = cacc[nd][r] * linv;
      *(float4v*)&cst[(widx * 16 + c) * 66 + nd * 16 + 4 * g] = v;
    }
    __syncthreads();
    const int qq = tid >> 2, ch = tid & 3;
    const float* src = &cst[qq * 66 + ch * 16];
    float* dst = outC + ((size_t)(bh * S_ + q0 + qq)) * D_ + ch * 16;
    float4v c0 = *(const float4v*)src;
    float4v c1 = *(const float4v*)(src + 4);
    float4v c2 = *(const float4v*)(src + 8);
    float4v c3 = *(const float4v*)(src + 12);
    __builtin_nontemporal_store(c0, (float4v*)dst);
    __builtin_nontemporal_store(c1, (float4v*)(dst + 4));
    __builtin_nontemporal_store(c2, (float4v*)(dst + 8));
    __builtin_nontemporal_store(c3, (float4v*)(dst + 12));
  }
}

// =============== Pass 2: QK -> exp -> xlinv -> full-line nt stores ===========
template <int PREP, int BM>
__global__ __launch_bounds__(256, 7) void k_store(
    const float* __restrict__ Q, const float* __restrict__ K,
    const float* __restrict__ scale_p, const uint8_t* __restrict__ M,
    const uint32_t* __restrict__ flag, const short* __restrict__ Kbf,
    const float* __restrict__ linvG, const uint32_t* __restrict__ mbitsG,
    float* __restrict__ outA)
{
  __shared__ uint32_t mbits2[64 * 65];
  __shared__ short eb2[4][16 * EBS];

  const int bx  = (blockIdx.x & 7) * 256 + (blockIdx.x >> 3);
  const int bh  = bx >> 5;                      // 32 blocks of 64 q-rows per bh
  const int q0  = (bx & 31) * 64;

  const int tid  = threadIdx.x;
  const int wv   = tid >> 6;                    // 0..3
  const int lane = tid & 63;
  const int g    = lane >> 4;
  const int c    = lane & 15;
  const int qrow = q0 + wv * 16 + c;

  const float scale = scale_p[0];
  const uint32_t fl = flag[0];

  const short* Kbp = Kbf + (size_t)bh * S_ * D_;
  const float* Kfp = K + (size_t)bh * S_ * D_;

  // ---- bitmap prologue: 64 rows ----
  {
    const int row = tid >> 2;                   // 0..63
    const int wq0 = (tid & 3) * 16;
    if (BM) {
      const uint32_t* mg = mbitsG + ((size_t)(bh * S_ + q0 + row)) * 64 + wq0;
#pragma unroll
      for (int k4 = 0; k4 < 4; ++k4) {
        uint4v v = __builtin_nontemporal_load((const uint4v*)(mg + k4 * 4));
        mbits2[row * 65 + wq0 + k4 * 4 + 0] = v.x;
        mbits2[row * 65 + wq0 + k4 * 4 + 1] = v.y;
        mbits2[row * 65 + wq0 + k4 * 4 + 2] = v.z;
        mbits2[row * 65 + wq0 + k4 * 4 + 3] = v.w;
      }
    } else if (fl == 3u) {
      const uint8_t* mrow = M + ((size_t)(bh * S_ + q0 + row)) * S_ + wq0 * 32;
#pragma unroll
      for (int j = 0; j < 16; ++j) {
        uint4v a = __builtin_nontemporal_load((const uint4v*)(mrow + j * 32));
        uint4v b = __builtin_nontemporal_load((const uint4v*)(mrow + j * 32 + 16));
        mbits2[row * 65 + wq0 + j] =
            nib(a.x) | (nib(a.y) << 4) | (nib(a.z) << 8)  | (nib(a.w) << 12)
          | (nib(b.x) << 16) | (nib(b.y) << 20) | (nib(b.z) << 24) | (nib(b.w) << 28);
      }
    } else {
      const uint32_t* mrow = (const uint32_t*)M + ((size_t)(bh * S_ + q0 + row)) * S_ + wq0 * 32;
#pragma unroll
      for (int j = 0; j < 16; ++j) {
        uint32_t bits = 0;
#pragma unroll
        for (int u = 0; u < 8; ++u) {
          uint4v wvv = __builtin_nontemporal_load((const uint4v*)(mrow + j * 32 + u * 4));
          uint32_t nzb = (wvv.x ? 1u : 0u) | (wvv.y ? 2u : 0u) | (wvv.z ? 4u : 0u) | (wvv.w ? 8u : 0u);
          bits |= nzb << (u * 4);
        }
        mbits2[row * 65 + wq0 + j] = bits;
      }
    }
  }

  // ---- Q as B-frag + per-row inverse sum (register) ----
  short8 qB[2];
  {
    const float* qr = Q + ((size_t)(bh * S_ + qrow)) * D_;
    float4v x0 = *(const float4v*)(qr + g * 8);
    float4v x1 = *(const float4v*)(qr + g * 8 + 4);
    float4v y0 = *(const float4v*)(qr + 32 + g * 8);
    float4v y1 = *(const float4v*)(qr + 32 + g * 8 + 4);
    short8 f;
    f[0]=f2bf(x0.x); f[1]=f2bf(x0.y); f[2]=f2bf(x0.z); f[3]=f2bf(x0.w);
    f[4]=f2bf(x1.x); f[5]=f2bf(x1.y); f[6]=f2bf(x1.z); f[7]=f2bf(x1.w);
    qB[0] = f;
    f[0]=f2bf(y0.x); f[1]=f2bf(y0.y); f[2]=f2bf(y0.z); f[3]=f2bf(y0.w);
    f[4]=f2bf(y1.x); f[5]=f2bf(y1.y); f[6]=f2bf(y1.z); f[7]=f2bf(y1.w);
    qB[1] = f;
  }
  const float linvq = linvG[(size_t)bh * S_ + qrow];
  __syncthreads();

  const uint32_t* mrow = &mbits2[(wv * 16 + c) * 65];
  short* eb = &eb2[wv][0];
  const int srow = lane >> 3;                   // 0..7
  const int scol = lane & 7;                    // 4-float chunk
  float* arow0 = outA + ((size_t)(bh * S_ + q0 + wv * 16 + srow)) * S_ + scol * 4;
  float* arow1 = outA + ((size_t)(bh * S_ + q0 + wv * 16 + srow + 8)) * S_ + scol * 4;

#pragma unroll 1
  for (int w = 0; w < NWIN; ++w) {
    const int kwin = w * 32;

    float4v acc0 = (float4v){0.f,0.f,0.f,0.f};
    float4v acc1 = (float4v){0.f,0.f,0.f,0.f};
    if (PREP) {
      const short* kr = Kbp + (size_t)(kwin + c) * D_ + g * 8;
      short8 a0 = *(const short8*)kr;
      short8 a1 = *(const short8*)(kr + 32);
      const short* kr1 = kr + 16 * D_;
      short8 a2 = *(const short8*)kr1;
      short8 a3 = *(const short8*)(kr1 + 32);
      acc0 = __builtin_amdgcn_mfma_f32_16x16x32_bf16(a0, qB[0], acc0, 0, 0, 0);
      acc0 = __builtin_amdgcn_mfma_f32_16x16x32_bf16(a1, qB[1], acc0, 0, 0, 0);
      acc1 = __builtin_amdgcn_mfma_f32_16x16x32_bf16(a2, qB[0], acc1, 0, 0, 0);
      acc1 = __builtin_amdgcn_mfma_f32_16x16x32_bf16(a3, qB[1], acc1, 0, 0, 0);
    } else {
      const float* kr = Kfp + (size_t)(kwin + c) * D_ + g * 8;
      const float* kr1 = kr + 16 * D_;
      short8 a0, a1, a2, a3;
#pragma unroll
      for (int e = 0; e < 8; ++e) {
        a0[e] = f2bf(kr[e]);  a1[e] = f2bf(kr[32 + e]);
        a2[e] = f2bf(kr1[e]); a3[e] = f2bf(kr1[32 + e]);
      }
      acc0 = __builtin_amdgcn_mfma_f32_16x16x32_bf16(a0, qB[0], acc0, 0, 0, 0);
      acc0 = __builtin_amdgcn_mfma_f32_16x16x32_bf16(a1, qB[1], acc0, 0, 0, 0);
      acc1 = __builtin_amdgcn_mfma_f32_16x16x32_bf16(a2, qB[0], acc1, 0, 0, 0);
      acc1 = __builtin_amdgcn_mfma_f32_16x16x32_bf16(a3, qB[1], acc1, 0, 0, 0);
    }

    const uint32_t mw = mrow[w];
    float n0[4], n1[4];
#pragma unroll
    for (int r = 0; r < 4; ++r) {
      n0[r] = (((mw >> (4 * g + r)) & 1u)      ? 1.0f : __expf(acc0[r] * scale)) * linvq;
      n1[r] = (((mw >> (16 + 4 * g + r)) & 1u) ? 1.0f : __expf(acc1[r] * scale)) * linvq;
    }
    uint2v lo, hi2;
    lo.x  = cvtpk(n0[0], n0[1]);  lo.y  = cvtpk(n0[2], n0[3]);
    hi2.x = cvtpk(n1[0], n1[1]);  hi2.y = cvtpk(n1[2], n1[3]);
    *(uint2v*)&eb[c * EBS + 4 * g]      = lo;
    *(uint2v*)&eb[c * EBS + 16 + 4 * g] = hi2;

    // full-128B-line stores: 8 rows per instruction (wave-private tile read)
    const uint2v ev0 = *(const uint2v*)&eb[srow * EBS + scol * 4];
    const uint2v ev1 = *(const uint2v*)&eb[(srow + 8) * EBS + scol * 4];
    float4v s0, s1;
    s0.x = bf2f(ev0.x & 0xffff); s0.y = bf2f(ev0.x >> 16);
    s0.z = bf2f(ev0.y & 0xffff); s0.w = bf2f(ev0.y >> 16);
    s1.x = bf2f(ev1.x & 0xffff); s1.y = bf2f(ev1.x >> 16);
    s1.z = bf2f(ev1.y & 0xffff); s1.w = bf2f(ev1.y >> 16);
    __builtin_nontemporal_store(s0, (float4v*)(arow0 + kwin));
    __builtin_nontemporal_store(s1, (float4v*)(arow1 + kwin));
  }
}

extern "C" void kernel_launch(void* const* d_in, const int* in_sizes, int n_in,
                              void* d_out, int out_size, void* d_ws, size_t ws_size,
                              hipStream_t stream) {
  const float*   Q     = (const float*)d_in[0];
  const float*   K     = (const float*)d_in[1];
  const float*   V     = (const float*)d_in[2];
  const float*   scale = (const float*)d_in[3];
  const uint8_t* M     = (const uint8_t*)d_in[4];
  uint32_t* flag  = (uint32_t*)d_ws;
  float*    linvG = (float*)((char*)d_ws + LINV_OFF);
  short*    Kbf   = (short*)((char*)d_ws + KBF_OFF);
  short*    VT    = (short*)((char*)d_ws + VT_OFF);
  uint32_t* mbG   = (uint32_t*)((char*)d_ws + MB_OFF);
  float* outC = (float*)d_out;
  float* outA = outC + (size_t)B_ * H_ * S_ * D_;

  hipMemsetAsync(flag, 0, 4, stream);
  detect_mask_dtype<<<dim3(1), dim3(256), 0, stream>>>(M, flag);

  const bool prep = ws_size >= VT_OFF + VT_BYTES;
  const bool bm   = ws_size >= MB_OFF + MB_BYTES;
  const int grid1 = B_ * H_ * (S_ / 128);       // 1024
  const int grid2 = B_ * H_ * (S_ / 64);        // 2048

  if (prep) {
    prep_k<<<dim3((B_ * H_ * S_ * D_) / (256 * 8)), dim3(256), 0, stream>>>(K, Kbf);
    prep_vt<<<dim3(B_ * H_ * (S_ / 64)), dim3(256), 0, stream>>>(V, VT);
    if (bm) {
      k_sums<1, 1><<<dim3(grid1), dim3(512), 0, stream>>>(
          Q, K, V, scale, M, flag, Kbf, VT, linvG, mbG, outC);
      k_store<1, 1><<<dim3(grid2), dim3(256), 0, stream>>>(
          Q, K, scale, M, flag, Kbf, linvG, mbG, outA);
    } else {
      k_sums<1, 0><<<dim3(grid1), dim3(512), 0, stream>>>(
          Q, K, V, scale, M, flag, Kbf, VT, linvG, mbG, outC);
      k_store<1, 0><<<dim3(grid2), dim3(256), 0, stream>>>(
          Q, K, scale, M, flag, Kbf, linvG, mbG, outA);
    }
  } else {
    k_sums<0, 0><<<dim3(grid1), dim3(512), 0, stream>>>(
        Q, K, V, scale, M, flag, Kbf, VT, linvG, mbG, outC);
    k_store<0, 0><<<dim3(grid2), dim3(256), 0, stream>>>(
        Q, K, scale, M, flag, Kbf, linvG, mbG, outA);
  }
}

// Round 18
// 824.419 us; speedup vs baseline: 1.6885x; 1.4524x over previous
//
#include <hip/hip_runtime.h>
#include <stdint.h>

#define B_ 4
#define H_ 16
#define S_ 2048
#define D_ 64
#define NWIN 64                       /* 32-k windows, full S */
#define EBS 40                        /* ebounce row stride (shorts) */
#define VBS 40                        /* vbuf row stride (shorts) */

typedef __attribute__((ext_vector_type(8))) short short8;
typedef __attribute__((ext_vector_type(4))) float float4v;
typedef __attribute__((ext_vector_type(4))) unsigned int uint4v;
typedef __attribute__((ext_vector_type(2))) unsigned int uint2v;

static __device__ __forceinline__ short f2bf(float f) {
  uint32_t u = __builtin_bit_cast(uint32_t, f);
  u = (u + 0x7FFFu + ((u >> 16) & 1u)) >> 16;   // RNE
  return (short)u;
}
static __device__ __forceinline__ float bf2f(uint32_t s) {
  return __builtin_bit_cast(float, s << 16);
}
static __device__ __forceinline__ uint32_t cvtpk(float lo, float hi) {
  uint32_t r;
  asm("v_cvt_pk_bf16_f32 %0, %1, %2" : "=v"(r) : "v"(lo), "v"(hi));
  return r;
}
static __device__ __forceinline__ uint32_t nz4(uint32_t d) {
  uint32_t x = (d & 0x7F7F7F7Fu) + 0x7F7F7F7Fu;
  x = (x | d) & 0x80808080u;
  return x >> 7;
}
static __device__ __forceinline__ uint32_t nib(uint32_t d) {
  return ((nz4(d) * 0x01020408u) >> 24) & 0xFu;
}

// workspace layout
#define LINV_OFF   ((size_t)64)
#define LINV_BYTES ((size_t)B_ * H_ * S_ * 4)            /* 512 KB */
#define KBF_OFF    (LINV_OFF + LINV_BYTES)
#define KBF_BYTES  ((size_t)B_ * H_ * S_ * D_ * 2)       /* 16 MB */
#define VT_OFF     (KBF_OFF + KBF_BYTES)
#define VT_BYTES   ((size_t)B_ * H_ * S_ * D_ * 2)       /* 16 MB */
#define MB_OFF     (VT_OFF + VT_BYTES)
#define MB_BYTES   ((size_t)B_ * H_ * S_ * 64 * 4)       /* 32 MB bitmap */

__global__ void detect_mask_dtype(const uint8_t* __restrict__ m, uint32_t* flag) {
  uint32_t a = 0, b = 0;
  for (int i = threadIdx.x; i < 65536; i += 256) {
    uint8_t x = m[i];
    if (i & 3) a |= x; else b |= x;
  }
  uint32_t bits = (a ? 1u : 0u) | (b ? 2u : 0u);
  if (bits) atomicOr(flag, bits);
}

__global__ __launch_bounds__(256) void prep_k(const float* __restrict__ K,
                                              short* __restrict__ Kbf) {
  size_t base = ((size_t)blockIdx.x * 256 + threadIdx.x) * 8;
  float4v a = *(const float4v*)(K + base);
  float4v b = *(const float4v*)(K + base + 4);
  short8 o;
  o[0]=f2bf(a.x); o[1]=f2bf(a.y); o[2]=f2bf(a.z); o[3]=f2bf(a.w);
  o[4]=f2bf(b.x); o[5]=f2bf(b.y); o[6]=f2bf(b.z); o[7]=f2bf(b.w);
  *(short8*)(Kbf + base) = o;
}

__global__ __launch_bounds__(256) void prep_vt(const float* __restrict__ V,
                                               short* __restrict__ VT) {
  __shared__ short tile[64][72];
  int bh = blockIdx.x >> 5, k0 = (blockIdx.x & 31) * 64;
  const float* src = V + ((size_t)bh * S_ + k0) * D_;
  int t = threadIdx.x;
  int r = t >> 2, c0 = (t & 3) * 16;
#pragma unroll
  for (int j = 0; j < 4; ++j) {
    float4v f = *(const float4v*)(src + (size_t)r * D_ + c0 + j * 4);
    tile[r][c0 + j*4 + 0] = f2bf(f.x);
    tile[r][c0 + j*4 + 1] = f2bf(f.y);
    tile[r][c0 + j*4 + 2] = f2bf(f.z);
    tile[r][c0 + j*4 + 3] = f2bf(f.w);
  }
  __syncthreads();
  int d = t >> 2, ks0 = (t & 3) * 16;
  short* dst = VT + (size_t)bh * D_ * S_ + (size_t)d * S_ + k0 + ks0;
#pragma unroll
  for (int half = 0; half < 2; ++half) {
    short8 o;
#pragma unroll
    for (int i = 0; i < 8; ++i) o[i] = tile[ks0 + half * 8 + i][d];
    *(short8*)(dst + half * 8) = o;
  }
}

// === Pass 1: rowsums (-> linvG) + PV + context; K AND V LDS-relayed ==========
template <int PREP, int BM>
__global__ __launch_bounds__(512, 6) void k_sums(
    const float* __restrict__ Q, const float* __restrict__ K,
    const float* __restrict__ V, const float* __restrict__ scale_p,
    const uint8_t* __restrict__ M, const uint32_t* __restrict__ flag,
    const short* __restrict__ Kbf, const short* __restrict__ VT,
    float* __restrict__ linvG, uint32_t* __restrict__ mbitsG,
    float* __restrict__ outC)
{
  __shared__ uint32_t mbits[128 * 66];          // mask stride 65; ctx-alias stride 66
  __shared__ short kbuf[2][32 * 64];            // K window dbuf (XOR-swizzled)
  __shared__ short vbuf[2][64 * VBS];           // V window dbuf [d][k] (padded)
  __shared__ short ebounce[8][16 * EBS];        // per-wave E bounce

  const int bx  = (blockIdx.x & 7) * 128 + (blockIdx.x >> 3);
  const int bh  = bx >> 4;
  const int q0  = (bx & 15) * 128;

  const int tid  = threadIdx.x;
  const int widx = tid >> 6;
  const int lane = tid & 63;
  const int g    = lane >> 4;
  const int c    = lane & 15;
  const int qrow = q0 + widx * 16 + c;

  const float scale = scale_p[0];
  const uint32_t fl = flag[0];

  const short* Kbp = Kbf + (size_t)bh * S_ * D_;
  const short* VTp = VT + (size_t)bh * D_ * S_;
  const float* Kfp = K + (size_t)bh * S_ * D_;
  const float* Vfp = V + (size_t)bh * S_ * D_;

  // ---- mask bitmap prologue: [128][2048] bits (stride 65), PLAIN loads ----
  {
    const int row = tid >> 2;
    const int wq0 = (tid & 3) * 16;
    if (fl == 3u) {
      const uint8_t* mrow = M + ((size_t)(bh * S_ + q0 + row)) * S_ + wq0 * 32;
#pragma unroll
      for (int j = 0; j < 16; ++j) {
        uint4v a = *(const uint4v*)(mrow + j * 32);
        uint4v b = *(const uint4v*)(mrow + j * 32 + 16);
        mbits[row * 65 + wq0 + j] =
            nib(a.x) | (nib(a.y) << 4) | (nib(a.z) << 8)  | (nib(a.w) << 12)
          | (nib(b.x) << 16) | (nib(b.y) << 20) | (nib(b.z) << 24) | (nib(b.w) << 28);
      }
    } else {
      const uint32_t* mrow = (const uint32_t*)M + ((size_t)(bh * S_ + q0 + row)) * S_ + wq0 * 32;
#pragma unroll
      for (int j = 0; j < 16; ++j) {
        uint32_t bits = 0;
#pragma unroll
        for (int u = 0; u < 8; ++u) {
          uint4v wv = *(const uint4v*)(mrow + j * 32 + u * 4);
          uint32_t nzb = (wv.x ? 1u : 0u) | (wv.y ? 2u : 0u) | (wv.z ? 4u : 0u) | (wv.w ? 8u : 0u);
          bits |= nzb << (u * 4);
        }
        mbits[row * 65 + wq0 + j] = bits;
      }
    }
  }

  // ---- Q as B-frag: lane holds Q[qrow][.] ----
  short8 qB[2];
  {
    const float* qr = Q + ((size_t)(bh * S_ + qrow)) * D_;
    float4v x0 = *(const float4v*)(qr + g * 8);
    float4v x1 = *(const float4v*)(qr + g * 8 + 4);
    float4v y0 = *(const float4v*)(qr + 32 + g * 8);
    float4v y1 = *(const float4v*)(qr + 32 + g * 8 + 4);
    short8 f;
    f[0]=f2bf(x0.x); f[1]=f2bf(x0.y); f[2]=f2bf(x0.z); f[3]=f2bf(x0.w);
    f[4]=f2bf(x1.x); f[5]=f2bf(x1.y); f[6]=f2bf(x1.z); f[7]=f2bf(x1.w);
    qB[0] = f;
    f[0]=f2bf(y0.x); f[1]=f2bf(y0.y); f[2]=f2bf(y0.z); f[3]=f2bf(y0.w);
    f[4]=f2bf(y1.x); f[5]=f2bf(y1.y); f[6]=f2bf(y1.z); f[7]=f2bf(y1.w);
    qB[1] = f;
  }

  // ---- staging: waves 0-3 relay K (XOR-swizzled), waves 4-7 relay V ----
  const bool kstager = (widx < 4);
  const bool vstager = (widx >= 4) && (PREP != 0);
  const int  sr = (widx << 3) + (lane >> 3);
  const int  sp = lane & 7;
  const int  sdst = sr * 64 + ((sp ^ (sr & 7)) << 3);
  const int  vr = ((widx - 4) << 4) + (lane >> 2);
  const int  vp = lane & 3;
  short8  kreg, vreg;
  float4v kf0, kf1;
#define ISSUE(W) do {                                                          \
    if (kstager) {                                                             \
      if (PREP) kreg = *(const short8*)(Kbp + (size_t)((W) * 32 + sr) * 64 + sp * 8); \
      else { const float* s_ = Kfp + (size_t)((W) * 32 + sr) * 64 + sp * 8;    \
             kf0 = *(const float4v*)s_; kf1 = *(const float4v*)(s_ + 4); }     \
    } else if (vstager) {                                                      \
      vreg = *(const short8*)(VTp + (size_t)vr * S_ + (W) * 32 + vp * 8);      \
    } } while (0)
#define WRITE(BUF) do {                                                        \
    if (kstager) {                                                             \
      short8 o_;                                                               \
      if (PREP) o_ = kreg;                                                     \
      else { o_[0]=f2bf(kf0.x); o_[1]=f2bf(kf0.y); o_[2]=f2bf(kf0.z); o_[3]=f2bf(kf0.w); \
             o_[4]=f2bf(kf1.x); o_[5]=f2bf(kf1.y); o_[6]=f2bf(kf1.z); o_[7]=f2bf(kf1.w); } \
      *(short8*)&kbuf[BUF][sdst] = o_;                                         \
    } else if (vstager) {                                                      \
      *(short8*)&vbuf[BUF][vr * VBS + vp * 8] = vreg;                          \
    } } while (0)

  const int ka0 = ((g       ^ (c & 7)) << 3);
  const int ka1 = (((g + 4) ^ (c & 7)) << 3);
  const uint32_t* mrow = &mbits[(widx * 16 + c) * 65];

  ISSUE(0); WRITE(0); ISSUE(1);
  __syncthreads();

  // ---- bitmap dump: linear, full-line NT stores (one LDS row per wave-instr) ----
  if (BM) {
    uint32_t* mg = mbitsG + ((size_t)(bh * S_ + q0)) * 64;
#pragma unroll
    for (int i = 0; i < 16; ++i) {
      const int wdx = i * 512 + tid;            // 0..8191
      const int row = wdx >> 6, wir = wdx & 63;
      __builtin_nontemporal_store(mbits[row * 65 + wir], mg + wdx);
    }
  }

  float rsv = 0.0f;
  float4v cacc[4];
#pragma unroll
  for (int nd = 0; nd < 4; ++nd) cacc[nd] = (float4v){0.f, 0.f, 0.f, 0.f};
  short* eb = &ebounce[widx][0];

#pragma unroll 1
  for (int w = 0; w < NWIN; ++w) {
    const int cur = w & 1;
    const int kwin = w * 32;

    short8 vA0, vA1, vA2, vA3;
    if (PREP) {
      const short* vb = &vbuf[cur][0];
      vA0 = *(const short8*)(vb + (size_t)(c)      * VBS + g * 8);
      vA1 = *(const short8*)(vb + (size_t)(16 + c) * VBS + g * 8);
      vA2 = *(const short8*)(vb + (size_t)(32 + c) * VBS + g * 8);
      vA3 = *(const short8*)(vb + (size_t)(48 + c) * VBS + g * 8);
    } else {
      const float* vc = Vfp + (size_t)(kwin + g * 8) * D_ + c;
#pragma unroll
      for (int e = 0; e < 8; ++e) {
        vA0[e] = f2bf(vc[(size_t)e * D_]);
        vA1[e] = f2bf(vc[(size_t)e * D_ + 16]);
        vA2[e] = f2bf(vc[(size_t)e * D_ + 32]);
        vA3[e] = f2bf(vc[(size_t)e * D_ + 48]);
      }
    }

    const short* kb = &kbuf[cur][0];
    short8 a0 = *(const short8*)(kb + c * 64 + ka0);
    short8 a1 = *(const short8*)(kb + c * 64 + ka1);
    short8 a2 = *(const short8*)(kb + (c + 16) * 64 + ka0);
    short8 a3 = *(const short8*)(kb + (c + 16) * 64 + ka1);

    float4v acc0 = (float4v){0.f,0.f,0.f,0.f};
    float4v acc1 = (float4v){0.f,0.f,0.f,0.f};
    acc0 = __builtin_amdgcn_mfma_f32_16x16x32_bf16(a0, qB[0], acc0, 0, 0, 0);
    acc0 = __builtin_amdgcn_mfma_f32_16x16x32_bf16(a1, qB[1], acc0, 0, 0, 0);
    acc1 = __builtin_amdgcn_mfma_f32_16x16x32_bf16(a2, qB[0], acc1, 0, 0, 0);
    acc1 = __builtin_amdgcn_mfma_f32_16x16x32_bf16(a3, qB[1], acc1, 0, 0, 0);

    const uint32_t mw = mrow[w];
    float e0[4], e1[4];
#pragma unroll
    for (int r = 0; r < 4; ++r) {
      e0[r] = ((mw >> (4 * g + r)) & 1u)      ? 1.0f : __expf(acc0[r] * scale);
      e1[r] = ((mw >> (16 + 4 * g + r)) & 1u) ? 1.0f : __expf(acc1[r] * scale);
      rsv += e0[r] + e1[r];
    }
    uint2v lo, hi2;
    lo.x  = cvtpk(e0[0], e0[1]);  lo.y  = cvtpk(e0[2], e0[3]);
    hi2.x = cvtpk(e1[0], e1[1]);  hi2.y = cvtpk(e1[2], e1[3]);
    *(uint2v*)&eb[c * EBS + 4 * g]      = lo;
    *(uint2v*)&eb[c * EBS + 16 + 4 * g] = hi2;
    const short8 bfrag = *(const short8*)&eb[c * EBS + g * 8];

    cacc[0] = __builtin_amdgcn_mfma_f32_16x16x32_bf16(vA0, bfrag, cacc[0], 0, 0, 0);
    cacc[1] = __builtin_amdgcn_mfma_f32_16x16x32_bf16(vA1, bfrag, cacc[1], 0, 0, 0);
    cacc[2] = __builtin_amdgcn_mfma_f32_16x16x32_bf16(vA2, bfrag, cacc[2], 0, 0, 0);
    cacc[3] = __builtin_amdgcn_mfma_f32_16x16x32_bf16(vA3, bfrag, cacc[3], 0, 0, 0);

    if (w + 1 < NWIN) {
      WRITE(cur ^ 1);
      if (w + 2 < NWIN) ISSUE(w + 2);
      __syncthreads();
    }
  }
#undef ISSUE
#undef WRITE

  rsv += __shfl_xor(rsv, 16);
  rsv += __shfl_xor(rsv, 32);
  const float linv = 1.0f / rsv;
  if (g == 0) linvG[(size_t)bh * S_ + qrow] = linv;
  __syncthreads();                              // mask dead; alias mbits for ctx

  // ---- context epilogue: normalize cacc, LDS transpose (stride 66), store ----
  {
    float* cst = (float*)mbits;                 // [128][66] floats
#pragma unroll
    for (int nd = 0; nd < 4; ++nd) {
      float4v v;
#pragma unroll
      for (int r = 0; r < 4; ++r) v[r] = cacc[nd][r] * linv;
      *(float4v*)&cst[(widx * 16 + c) * 66 + nd * 16 + 4 * g] = v;
    }
    __syncthreads();
    const int qq = tid >> 2, ch = tid & 3;
    const float* src = &cst[qq * 66 + ch * 16];
    float* dst = outC + ((size_t)(bh * S_ + q0 + qq)) * D_ + ch * 16;
    float4v c0 = *(const float4v*)src;
    float4v c1 = *(const float4v*)(src + 4);
    float4v c2 = *(const float4v*)(src + 8);
    float4v c3 = *(const float4v*)(src + 12);
    __builtin_nontemporal_store(c0, (float4v*)dst);
    __builtin_nontemporal_store(c1, (float4v*)(dst + 4));
    __builtin_nontemporal_store(c2, (float4v*)(dst + 8));
    __builtin_nontemporal_store(c3, (float4v*)(dst + 12));
  }
}

// =============== Pass 2: QK -> exp -> xlinv -> full-line nt stores ===========
template <int PREP, int BM>
__global__ __launch_bounds__(256, 7) void k_store(
    const float* __restrict__ Q, const float* __restrict__ K,
    const float* __restrict__ scale_p, const uint8_t* __restrict__ M,
    const uint32_t* __restrict__ flag, const short* __restrict__ Kbf,
    const float* __restrict__ linvG, const uint32_t* __restrict__ mbitsG,
    float* __restrict__ outA)
{
  __shared__ uint32_t mbits2[64 * 68];          // stride 68 (16B-aligned rows)
  __shared__ short eb2[4][16 * EBS];

  const int bx  = (blockIdx.x & 7) * 256 + (blockIdx.x >> 3);
  const int bh  = bx >> 5;
  const int q0  = (bx & 31) * 64;

  const int tid  = threadIdx.x;
  const int wv   = tid >> 6;
  const int lane = tid & 63;
  const int g    = lane >> 4;
  const int c    = lane & 15;
  const int qrow = q0 + wv * 16 + c;

  const float scale = scale_p[0];
  const uint32_t fl = flag[0];

  const short* Kbp = Kbf + (size_t)bh * S_ * D_;
  const float* Kfp = K + (size_t)bh * S_ * D_;

  // ---- bitmap prologue: 64 rows (stride 68) ----
  if (BM) {
    // linear full-line loads: 4 KB contiguous per instruction
    const uint32_t* mg = mbitsG + ((size_t)(bh * S_ + q0)) * 64;
#pragma unroll
    for (int i = 0; i < 4; ++i) {
      const int idx4 = i * 256 + tid;           // uint4 index 0..1023
      uint4v v = *(const uint4v*)(mg + (size_t)idx4 * 4);
      const int w0 = idx4 * 4, row = w0 >> 6, wir = w0 & 63;
      *(uint4v*)&mbits2[row * 68 + wir] = v;
    }
  } else {
    const int row = tid >> 2;
    const int wq0 = (tid & 3) * 16;
    if (fl == 3u) {
      const uint8_t* mrow = M + ((size_t)(bh * S_ + q0 + row)) * S_ + wq0 * 32;
#pragma unroll
      for (int j = 0; j < 16; ++j) {
        uint4v a = *(const uint4v*)(mrow + j * 32);
        uint4v b = *(const uint4v*)(mrow + j * 32 + 16);
        mbits2[row * 68 + wq0 + j] =
            nib(a.x) | (nib(a.y) << 4) | (nib(a.z) << 8)  | (nib(a.w) << 12)
          | (nib(b.x) << 16) | (nib(b.y) << 20) | (nib(b.z) << 24) | (nib(b.w) << 28);
      }
    } else {
      const uint32_t* mrow = (const uint32_t*)M + ((size_t)(bh * S_ + q0 + row)) * S_ + wq0 * 32;
#pragma unroll
      for (int j = 0; j < 16; ++j) {
        uint32_t bits = 0;
#pragma unroll
        for (int u = 0; u < 8; ++u) {
          uint4v wvv = *(const uint4v*)(mrow + j * 32 + u * 4);
          uint32_t nzb = (wvv.x ? 1u : 0u) | (wvv.y ? 2u : 0u) | (wvv.z ? 4u : 0u) | (wvv.w ? 8u : 0u);
          bits |= nzb << (u * 4);
        }
        mbits2[row * 68 + wq0 + j] = bits;
      }
    }
  }

  // ---- Q as B-frag + per-row inverse sum (register) ----
  short8 qB[2];
  {
    const float* qr = Q + ((size_t)(bh * S_ + qrow)) * D_;
    float4v x0 = *(const float4v*)(qr + g * 8);
    float4v x1 = *(const float4v*)(qr + g * 8 + 4);
    float4v y0 = *(const float4v*)(qr + 32 + g * 8);
    float4v y1 = *(const float4v*)(qr + 32 + g * 8 + 4);
    short8 f;
    f[0]=f2bf(x0.x); f[1]=f2bf(x0.y); f[2]=f2bf(x0.z); f[3]=f2bf(x0.w);
    f[4]=f2bf(x1.x); f[5]=f2bf(x1.y); f[6]=f2bf(x1.z); f[7]=f2bf(x1.w);
    qB[0] = f;
    f[0]=f2bf(y0.x); f[1]=f2bf(y0.y); f[2]=f2bf(y0.z); f[3]=f2bf(y0.w);
    f[4]=f2bf(y1.x); f[5]=f2bf(y1.y); f[6]=f2bf(y1.z); f[7]=f2bf(y1.w);
    qB[1] = f;
  }
  const float linvq = linvG[(size_t)bh * S_ + qrow];
  __syncthreads();

  const uint32_t* mrow = &mbits2[(wv * 16 + c) * 68];
  short* eb = &eb2[wv][0];
  const int srow = lane >> 3;
  const int scol = lane & 7;
  float* arow0 = outA + ((size_t)(bh * S_ + q0 + wv * 16 + srow)) * S_ + scol * 4;
  float* arow1 = outA + ((size_t)(bh * S_ + q0 + wv * 16 + srow + 8)) * S_ + scol * 4;

#pragma unroll 1
  for (int w = 0; w < NWIN; ++w) {
    const int kwin = w * 32;

    float4v acc0 = (float4v){0.f,0.f,0.f,0.f};
    float4v acc1 = (float4v){0.f,0.f,0.f,0.f};
    if (PREP) {
      const short* kr = Kbp + (size_t)(kwin + c) * D_ + g * 8;
      short8 a0 = *(const short8*)kr;
      short8 a1 = *(const short8*)(kr + 32);
      const short* kr1 = kr + 16 * D_;
      short8 a2 = *(const short8*)kr1;
      short8 a3 = *(const short8*)(kr1 + 32);
      acc0 = __builtin_amdgcn_mfma_f32_16x16x32_bf16(a0, qB[0], acc0, 0, 0, 0);
      acc0 = __builtin_amdgcn_mfma_f32_16x16x32_bf16(a1, qB[1], acc0, 0, 0, 0);
      acc1 = __builtin_amdgcn_mfma_f32_16x16x32_bf16(a2, qB[0], acc1, 0, 0, 0);
      acc1 = __builtin_amdgcn_mfma_f32_16x16x32_bf16(a3, qB[1], acc1, 0, 0, 0);
    } else {
      const float* kr = Kfp + (size_t)(kwin + c) * D_ + g * 8;
      const float* kr1 = kr + 16 * D_;
      short8 a0, a1, a2, a3;
#pragma unroll
      for (int e = 0; e < 8; ++e) {
        a0[e] = f2bf(kr[e]);  a1[e] = f2bf(kr[32 + e]);
        a2[e] = f2bf(kr1[e]); a3[e] = f2bf(kr1[32 + e]);
      }
      acc0 = __builtin_amdgcn_mfma_f32_16x16x32_bf16(a0, qB[0], acc0, 0, 0, 0);
      acc0 = __builtin_amdgcn_mfma_f32_16x16x32_bf16(a1, qB[1], acc0, 0, 0, 0);
      acc1 = __builtin_amdgcn_mfma_f32_16x16x32_bf16(a2, qB[0], acc1, 0, 0, 0);
      acc1 = __builtin_amdgcn_mfma_f32_16x16x32_bf16(a3, qB[1], acc1, 0, 0, 0);
    }

    const uint32_t mw = mrow[w];
    float n0[4], n1[4];
#pragma unroll
    for (int r = 0; r < 4; ++r) {
      n0[r] = (((mw >> (4 * g + r)) & 1u)      ? 1.0f : __expf(acc0[r] * scale)) * linvq;
      n1[r] = (((mw >> (16 + 4 * g + r)) & 1u) ? 1.0f : __expf(acc1[r] * scale)) * linvq;
    }
    uint2v lo, hi2;
    lo.x  = cvtpk(n0[0], n0[1]);  lo.y  = cvtpk(n0[2], n0[3]);
    hi2.x = cvtpk(n1[0], n1[1]);  hi2.y = cvtpk(n1[2], n1[3]);
    *(uint2v*)&eb[c * EBS + 4 * g]      = lo;
    *(uint2v*)&eb[c * EBS + 16 + 4 * g] = hi2;

    const uint2v ev0 = *(const uint2v*)&eb[srow * EBS + scol * 4];
    const uint2v ev1 = *(const uint2v*)&eb[(srow + 8) * EBS + scol * 4];
    float4v s0, s1;
    s0.x = bf2f(ev0.x & 0xffff); s0.y = bf2f(ev0.x >> 16);
    s0.z = bf2f(ev0.y & 0xffff); s0.w = bf2f(ev0.y >> 16);
    s1.x = bf2f(ev1.x & 0xffff); s1.y = bf2f(ev1.x >> 16);
    s1.z = bf2f(ev1.y & 0xffff); s1.w = bf2f(ev1.y >> 16);
    __builtin_nontemporal_store(s0, (float4v*)(arow0 + kwin));
    __builtin_nontemporal_store(s1, (float4v*)(arow1 + kwin));
  }
}

extern "C" void kernel_launch(void* const* d_in, const int* in_sizes, int n_in,
                              void* d_out, int out_size, void* d_ws, size_t ws_size,
                              hipStream_t stream) {
  const float*   Q     = (const float*)d_in[0];
  const float*   K     = (const float*)d_in[1];
  const float*   V     = (const float*)d_in[2];
  const float*   scale = (const float*)d_in[3];
  const uint8_t* M     = (const uint8_t*)d_in[4];
  uint32_t* flag  = (uint32_t*)d_ws;
  float*    linvG = (float*)((char*)d_ws + LINV_OFF);
  short*    Kbf   = (short*)((char*)d_ws + KBF_OFF);
  short*    VT    = (short*)((char*)d_ws + VT_OFF);
  uint32_t* mbG   = (uint32_t*)((char*)d_ws + MB_OFF);
  float* outC = (float*)d_out;
  float* outA = outC + (size_t)B_ * H_ * S_ * D_;

  hipMemsetAsync(flag, 0, 4, stream);
  detect_mask_dtype<<<dim3(1), dim3(256), 0, stream>>>(M, flag);

  const bool prep = ws_size >= VT_OFF + VT_BYTES;
  const bool bm   = ws_size >= MB_OFF + MB_BYTES;
  const int grid1 = B_ * H_ * (S_ / 128);       // 1024
  const int grid2 = B_ * H_ * (S_ / 64);        // 2048

  if (prep) {
    prep_k<<<dim3((B_ * H_ * S_ * D_) / (256 * 8)), dim3(256), 0, stream>>>(K, Kbf);
    prep_vt<<<dim3(B_ * H_ * (S_ / 64)), dim3(256), 0, stream>>>(V, VT);
    if (bm) {
      k_sums<1, 1><<<dim3(grid1), dim3(512), 0, stream>>>(
          Q, K, V, scale, M, flag, Kbf, VT, linvG, mbG, outC);
      k_store<1, 1><<<dim3(grid2), dim3(256), 0, stream>>>(
          Q, K, scale, M, flag, Kbf, linvG, mbG, outA);
    } else {
      k_sums<1, 0><<<dim3(grid1), dim3(512), 0, stream>>>(
          Q, K, V, scale, M, flag, Kbf, VT, linvG, mbG, outC);
      k_store<1, 0><<<dim3(grid2), dim3(256), 0, stream>>>(
          Q, K, scale, M, flag, Kbf, linvG, mbG, outA);
    }
  } else {
    k_sums<0, 0><<<dim3(grid1), dim3(512), 0, stream>>>(
        Q, K, V, scale, M, flag, Kbf, VT, linvG, mbG, outC);
    k_store<0, 0><<<dim3(grid2), dim3(256), 0, stream>>>(
        Q, K, scale, M, flag, Kbf, linvG, mbG, outA);
  }
}